// Round 3
// baseline (1259.716 us; speedup 1.0000x reference)
//
#include <hip/hip_runtime.h>
#include <stdint.h>

#define D_IN 512
#define D_HID 256

__device__ __forceinline__ float b2f(unsigned short u) {
    union { float f; uint32_t i; } x; x.i = ((uint32_t)u) << 16; return x.f;
}
__device__ __forceinline__ unsigned short f2b(float f) {
    union { float f; uint32_t i; } x; x.f = f;
    uint32_t i = x.i;
    uint32_t r = (i + 0x7FFFu + ((i >> 16) & 1u)) >> 16;
    return (unsigned short)r;
}

// ---------- dtype detector: flag=1 if raw bits are float32, 0 if bf16 ----------
// f32 bit pattern -> low-half ushorts ~uniform -> bf16-exp==0xFF hits expected ~256 in 64K.
// genuine bf16 N(0,1) data never has exp==0xFF.
__global__ void detect_dtype_kernel(const unsigned short* __restrict__ raw, int nscan,
                                    int* __restrict__ flag) {
    __shared__ int any;
    if (threadIdx.x == 0) any = 0;
    __syncthreads();
    int hit = 0;
    for (int i = threadIdx.x; i < nscan; i += blockDim.x) {
        unsigned short u = raw[i];
        if (((u >> 7) & 0xFF) == 0xFF) hit = 1;
    }
    if (hit) atomicAdd(&any, 1);
    __syncthreads();
    if (threadIdx.x == 0) *flag = (any != 0) ? 1 : 0;
}

// ---------- degree histogram / scan / CSR scatter ----------
__global__ void hist_kernel(const int* __restrict__ dst, int* __restrict__ counts, int E) {
    int e = blockIdx.x * blockDim.x + threadIdx.x;
    if (e < E) atomicAdd(&counts[dst[e]], 1);
}

__global__ void scan_kernel(const int* __restrict__ counts, int* __restrict__ indptr,
                            int* __restrict__ cursor, float* __restrict__ dinv, int n) {
    __shared__ int sh[1024];
    __shared__ int carry_s;
    if (threadIdx.x == 0) carry_s = 0;
    __syncthreads();
    int nch = (n + 1023) >> 10;
    for (int c = 0; c < nch; ++c) {
        int i = (c << 10) + threadIdx.x;
        int v = (i < n) ? counts[i] : 0;
        sh[threadIdx.x] = v;
        __syncthreads();
        for (int off = 1; off < 1024; off <<= 1) {
            int t = (threadIdx.x >= off) ? sh[threadIdx.x - off] : 0;
            __syncthreads();
            sh[threadIdx.x] += t;
            __syncthreads();
        }
        int incl = sh[threadIdx.x];
        int base = carry_s;
        __syncthreads();
        if (i < n) {
            int e = base + incl - v;
            indptr[i] = e;
            cursor[i] = e;
            dinv[i] = rsqrtf((float)(v + 1));  // self-loop => deg >= 1 always
        }
        if (threadIdx.x == 1023) carry_s = base + incl;
        __syncthreads();
    }
    if (threadIdx.x == 0) indptr[n] = carry_s;
}

__global__ void scatter_kernel(const int* __restrict__ src, const int* __restrict__ dst,
                               int* __restrict__ cursor, int* __restrict__ csr_src, int E) {
    int e = blockIdx.x * blockDim.x + threadIdx.x;
    if (e < E) {
        int d = dst[e];
        int pos = atomicAdd(&cursor[d], 1);
        csr_src[pos] = src[e];
    }
}

// ---------- VALU f32 GEMM: C[M,256] = A[M,K] @ W[K,256] ----------
// block = 256 thr, tile 16 rows x 256 cols. A tile staged transposed in LDS
// (stride 20 keeps float4 16B-aligned). wave = 16r x 64c, thread = 4r x 4c.
template<int K, bool AF32, bool WF32>
__device__ __forceinline__ void gemm_body(const void* __restrict__ Av,
        const void* __restrict__ Wv, float* __restrict__ C, int M, int row0, float* As) {
    const float* A32 = (const float*)Av;
    const unsigned short* A16 = (const unsigned short*)Av;
    const float* W32 = (const float*)Wv;
    const unsigned short* W16 = (const unsigned short*)Wv;
    int t = threadIdx.x;
    for (int i = t; i < 16 * K; i += 256) {
        int r = i / K;
        int k = i - r * K;
        int row = row0 + r;
        float v = 0.f;
        if (row < M)
            v = AF32 ? A32[(size_t)row * K + k] : b2f(A16[(size_t)row * K + k]);
        As[k * 20 + r] = v;
    }
    __syncthreads();
    int lane = t & 63, wave = t >> 6;
    int c0 = wave * 64 + (lane & 15) * 4;
    int r0 = (lane >> 4) * 4;
    float acc[4][4];
#pragma unroll
    for (int r = 0; r < 4; ++r)
#pragma unroll
        for (int c = 0; c < 4; ++c) acc[r][c] = 0.f;
#pragma unroll 4
    for (int k = 0; k < K; ++k) {
        float4 av = *(const float4*)(As + k * 20 + r0);
        float4 wv;
        if (WF32) {
            wv = *(const float4*)(W32 + (size_t)k * 256 + c0);
        } else {
            ushort4 wu = *(const ushort4*)(W16 + (size_t)k * 256 + c0);
            wv.x = b2f(wu.x); wv.y = b2f(wu.y); wv.z = b2f(wu.z); wv.w = b2f(wu.w);
        }
        float ar[4] = {av.x, av.y, av.z, av.w};
#pragma unroll
        for (int r = 0; r < 4; ++r) {
            acc[r][0] += ar[r] * wv.x;
            acc[r][1] += ar[r] * wv.y;
            acc[r][2] += ar[r] * wv.z;
            acc[r][3] += ar[r] * wv.w;
        }
    }
#pragma unroll
    for (int r = 0; r < 4; ++r) {
        int row = row0 + r0 + r;
        if (row < M) {
            float4 o = {acc[r][0], acc[r][1], acc[r][2], acc[r][3]};
            *(float4*)(C + (size_t)row * 256 + c0) = o;
        }
    }
}

template<int K>
__global__ __launch_bounds__(256) void gemm_kernel(const void* __restrict__ A,
        const void* __restrict__ W, float* __restrict__ C, int M,
        const int* __restrict__ flag, int a_forced_f32) {
    __shared__ float As[K * 20];
    int row0 = blockIdx.x * 16;
    bool wf = (*flag != 0);
    if (wf)
        gemm_body<K, true, true>(A, W, C, M, row0, As);
    else if (a_forced_f32)
        gemm_body<K, true, false>(A, W, C, M, row0, As);
    else
        gemm_body<K, false, false>(A, W, C, M, row0, As);
}

// ---------- GCN aggregation (f32 h): out[v] = dinv[v]*(sum_in dinv[s]*h[s] + dinv[v]*h[v]) + b ----------
__global__ __launch_bounds__(256) void aggregate_kernel(const float* __restrict__ h,
        const int* __restrict__ indptr, const int* __restrict__ csr_src,
        const float* __restrict__ dinv, const void* __restrict__ bias,
        float* __restrict__ out, int n, int do_relu, const int* __restrict__ flag) {
    int wave = threadIdx.x >> 6;
    int lane = threadIdx.x & 63;
    int v = blockIdx.x * 4 + wave;
    if (v >= n) return;
    int beg = indptr[v];
    int end = indptr[v + 1];
    float dv = dinv[v];
    float4 hv = *(const float4*)(h + (size_t)v * 256 + lane * 4);
    float a0 = dv * hv.x, a1 = dv * hv.y, a2 = dv * hv.z, a3 = dv * hv.w;
    for (int e = beg; e < end; ++e) {
        int s = csr_src[e];
        float w = dinv[s];
        float4 hs = *(const float4*)(h + (size_t)s * 256 + lane * 4);
        a0 += w * hs.x; a1 += w * hs.y; a2 += w * hs.z; a3 += w * hs.w;
    }
    float4 bb;
    if (*flag != 0) {
        bb = *(const float4*)((const float*)bias + lane * 4);
    } else {
        ushort4 bu = *(const ushort4*)((const unsigned short*)bias + lane * 4);
        bb.x = b2f(bu.x); bb.y = b2f(bu.y); bb.z = b2f(bu.z); bb.w = b2f(bu.w);
    }
    float o0 = dv * a0 + bb.x;
    float o1 = dv * a1 + bb.y;
    float o2 = dv * a2 + bb.z;
    float o3 = dv * a3 + bb.w;
    if (do_relu) {
        o0 = fmaxf(o0, 0.f); o1 = fmaxf(o1, 0.f); o2 = fmaxf(o2, 0.f); o3 = fmaxf(o3, 0.f);
    }
    float4 ov = {o0, o1, o2, o3};
    *(float4*)(out + (size_t)v * 256 + lane * 4) = ov;
}

// ---------- edge scoring: sigmoid(dot(h[src], h[dst])) ----------
// Output dtype follows detected input dtype: f32 inputs -> f32 out, bf16 -> bf16 out.
__global__ __launch_bounds__(256) void edge_score_kernel(const float* __restrict__ h,
        const int* __restrict__ src, const int* __restrict__ dst,
        void* __restrict__ out, int E, const int* __restrict__ flag) {
    int wave = threadIdx.x >> 6;
    int lane = threadIdx.x & 63;
    int e = blockIdx.x * 4 + wave;
    if (e >= E) return;
    int s = src[e], d = dst[e];
    float4 ha = *(const float4*)(h + (size_t)s * 256 + lane * 4);
    float4 hb = *(const float4*)(h + (size_t)d * 256 + lane * 4);
    float p = ha.x * hb.x + ha.y * hb.y + ha.z * hb.z + ha.w * hb.w;
#pragma unroll
    for (int off = 32; off > 0; off >>= 1) p += __shfl_xor(p, off, 64);
    if (lane == 0) {
        float prob = 1.f / (1.f + __expf(-p));
        if (*flag != 0)
            ((float*)out)[e] = prob;
        else
            ((unsigned short*)out)[e] = f2b(prob);
    }
}

extern "C" void kernel_launch(void* const* d_in, const int* in_sizes, int n_in,
                              void* d_out, int out_size, void* d_ws, size_t ws_size,
                              hipStream_t stream) {
    const void* x  = d_in[0];
    const int* edge_index = (const int*)d_in[1];
    const void* W1 = d_in[2];
    const void* b1 = d_in[3];
    const void* W2 = d_in[4];
    const void* b2 = d_in[5];

    const int N = in_sizes[0] / D_IN;   // 50000
    const int E = in_sizes[1] / 2;      // 800000
    const int* src = edge_index;
    const int* dst = edge_index + E;

    char* ws = (char*)d_ws;
    size_t off = 0;
    auto alloc = [&](size_t bytes) {
        char* p = ws + off;
        off = (off + bytes + 255) & ~(size_t)255;
        return p;
    };
    int* flag     = (int*)alloc(256);
    float* dinv   = (float*)alloc((size_t)N * 4);
    int* counts   = (int*)alloc((size_t)N * 4);
    int* indptr   = (int*)alloc((size_t)(N + 1) * 4);
    int* cursor   = (int*)alloc((size_t)N * 4);
    int* csr_src  = (int*)alloc((size_t)E * 4);
    float* hA     = (float*)alloc((size_t)N * 256 * 4);   // 51.2 MB
    float* hB     = (float*)alloc((size_t)N * 256 * 4);   // 51.2 MB

    detect_dtype_kernel<<<1, 256, 0, stream>>>((const unsigned short*)x, 65536, flag);
    hipMemsetAsync(counts, 0, (size_t)N * 4, stream);
    hist_kernel<<<(E + 255) / 256, 256, 0, stream>>>(dst, counts, E);
    scan_kernel<<<1, 1024, 0, stream>>>(counts, indptr, cursor, dinv, N);
    scatter_kernel<<<(E + 255) / 256, 256, 0, stream>>>(src, dst, cursor, csr_src, E);

    int ggrid = (N + 15) / 16;
    gemm_kernel<D_IN><<<ggrid, 256, 0, stream>>>(x, W1, hA, N, flag, 0);
    aggregate_kernel<<<(N + 3) / 4, 256, 0, stream>>>(hA, indptr, csr_src, dinv, b1, hB, N, 1, flag);
    gemm_kernel<D_HID><<<ggrid, 256, 0, stream>>>(hB, W2, hA, N, flag, 1);
    aggregate_kernel<<<(N + 3) / 4, 256, 0, stream>>>(hA, indptr, csr_src, dinv, b2, hB, N, 0, flag);
    edge_score_kernel<<<(E + 3) / 4, 256, 0, stream>>>(hB, src, dst, d_out, E, flag);
}

// Round 4
// 1083.722 us; speedup vs baseline: 1.1624x; 1.1624x over previous
//
#include <hip/hip_runtime.h>
#include <stdint.h>

#define D_IN 512
#define D_HID 256

typedef __attribute__((ext_vector_type(8))) short bf16x8;
typedef __attribute__((ext_vector_type(4))) float f32x4;

__device__ __forceinline__ float b2f(unsigned short u) {
    union { float f; uint32_t i; } x; x.i = ((uint32_t)u) << 16; return x.f;
}
__device__ __forceinline__ unsigned short f2b(float f) {
    union { float f; uint32_t i; } x; x.f = f;
    uint32_t i = x.i;
    uint32_t r = (i + 0x7FFFu + ((i >> 16) & 1u)) >> 16;
    return (unsigned short)r;
}

// ---------- dtype detector: flag=1 if raw bits are float32, 0 if bf16 ----------
__global__ void detect_dtype_kernel(const unsigned short* __restrict__ raw, int nscan,
                                    int* __restrict__ flag) {
    __shared__ int any;
    if (threadIdx.x == 0) any = 0;
    __syncthreads();
    int hit = 0;
    for (int i = threadIdx.x; i < nscan; i += blockDim.x) {
        unsigned short u = raw[i];
        if (((u >> 7) & 0xFF) == 0xFF) hit = 1;
    }
    if (hit) atomicAdd(&any, 1);
    __syncthreads();
    if (threadIdx.x == 0) *flag = (any != 0) ? 1 : 0;
}

// ---------- degree histogram / scan / CSR scatter ----------
__global__ void hist_kernel(const int* __restrict__ dst, int* __restrict__ counts, int E) {
    int e = blockIdx.x * blockDim.x + threadIdx.x;
    if (e < E) atomicAdd(&counts[dst[e]], 1);
}

__global__ void scan_kernel(const int* __restrict__ counts, int* __restrict__ indptr,
                            int* __restrict__ cursor, float* __restrict__ dinv, int n) {
    __shared__ int sh[1024];
    __shared__ int carry_s;
    if (threadIdx.x == 0) carry_s = 0;
    __syncthreads();
    int nch = (n + 1023) >> 10;
    for (int c = 0; c < nch; ++c) {
        int i = (c << 10) + threadIdx.x;
        int v = (i < n) ? counts[i] : 0;
        sh[threadIdx.x] = v;
        __syncthreads();
        for (int off = 1; off < 1024; off <<= 1) {
            int t = (threadIdx.x >= off) ? sh[threadIdx.x - off] : 0;
            __syncthreads();
            sh[threadIdx.x] += t;
            __syncthreads();
        }
        int incl = sh[threadIdx.x];
        int base = carry_s;
        __syncthreads();
        if (i < n) {
            int e = base + incl - v;
            indptr[i] = e;
            cursor[i] = e;
            dinv[i] = rsqrtf((float)(v + 1));  // self-loop => deg >= 1 always
        }
        if (threadIdx.x == 1023) carry_s = base + incl;
        __syncthreads();
    }
    if (threadIdx.x == 0) indptr[n] = carry_s;
}

__global__ void scatter_kernel(const int* __restrict__ src, const int* __restrict__ dst,
                               int* __restrict__ cursor, int* __restrict__ csr_src, int E) {
    int e = blockIdx.x * blockDim.x + threadIdx.x;
    if (e < E) {
        int d = dst[e];
        int pos = atomicAdd(&cursor[d], 1);
        csr_src[pos] = src[e];
    }
}

// ---------- W transpose + bf16 hi/lo split: W[K][256] -> WThi/WTlo [256][K] ----------
__global__ void wsplit_kernel(const void* __restrict__ W, unsigned short* __restrict__ WThi,
                              unsigned short* __restrict__ WTlo, int K,
                              const int* __restrict__ flag) {
    int idx = blockIdx.x * blockDim.x + threadIdx.x;
    if (idx >= K * 256) return;
    int k = idx >> 8;
    int n = idx & 255;
    float v = (*flag != 0) ? ((const float*)W)[idx] : b2f(((const unsigned short*)W)[idx]);
    unsigned short h = f2b(v);
    float r = v - b2f(h);
    WThi[n * K + k] = h;
    WTlo[n * K + k] = f2b(r);
}

// ---------- split-bf16 MFMA GEMM: C[M,256] = A[M,K] @ W[K,256] ----------
// wave: 32 rows x 256 cols (2 rowsets of 16). 16x16x32 bf16 MFMA.
// A frag: lane holds A[m=lane&15][kk*32 + (lane>>4)*8 + j] — 16B contiguous.
// B frag: lane holds B[k][n=lane&15], k = kk*32 + (lane>>4)*8 + j — contiguous in WT[n][k].
// C/D: col = lane&15, row = (lane>>4)*4 + reg  [measured m89].
// Split: A = Ah + Al, W = Wh + Wl; acc += Ah*Wh + Al*Wh + Ah*Wl  (rel err ~2e-5).
__device__ __forceinline__ void load_split_f32(const float* p, bf16x8& hi, bf16x8& lo) {
    float4 v0 = *(const float4*)p;
    float4 v1 = *(const float4*)(p + 4);
    float vv[8] = {v0.x, v0.y, v0.z, v0.w, v1.x, v1.y, v1.z, v1.w};
#pragma unroll
    for (int j = 0; j < 8; ++j) {
        unsigned short h = f2b(vv[j]);
        float r = vv[j] - b2f(h);
        hi[j] = (short)h;
        lo[j] = (short)f2b(r);
    }
}

template<int K>
__global__ __launch_bounds__(256) void gemm_mfma_split(const void* __restrict__ A,
        const unsigned short* __restrict__ WThi, const unsigned short* __restrict__ WTlo,
        float* __restrict__ C, int M, const int* __restrict__ flag, int a_forced_f32) {
    int lane = threadIdx.x & 63;
    int wv = threadIdx.x >> 6;
    int tile = blockIdx.x * 128 + wv * 32;   // base row of this wave
    if (tile >= M) return;
    int n0 = lane & 15;
    int grp = lane >> 4;
    bool af32 = a_forced_f32 || (*flag != 0);
    const float* A32 = (const float*)A;
    const unsigned short* A16 = (const unsigned short*)A;
    int ra = min(tile + n0, M - 1);
    int rb = min(tile + 16 + n0, M - 1);

    f32x4 acc[2][16];
#pragma unroll
    for (int rs = 0; rs < 2; ++rs)
#pragma unroll
        for (int t = 0; t < 16; ++t) acc[rs][t] = (f32x4){0.f, 0.f, 0.f, 0.f};

    for (int kk = 0; kk < K / 32; ++kk) {
        int kof = kk * 32 + grp * 8;
        bf16x8 ah0, al0, ah1, al1;
        if (af32) {
            load_split_f32(A32 + (size_t)ra * K + kof, ah0, al0);
            load_split_f32(A32 + (size_t)rb * K + kof, ah1, al1);
        } else {
            ah0 = *(const bf16x8*)(A16 + (size_t)ra * K + kof);
            ah1 = *(const bf16x8*)(A16 + (size_t)rb * K + kof);
            al0 = (bf16x8)(short)0;
            al1 = (bf16x8)(short)0;
        }
#pragma unroll
        for (int t = 0; t < 16; ++t) {
            size_t bo = (size_t)(t * 16 + n0) * K + kof;
            bf16x8 bh = *(const bf16x8*)(WThi + bo);
            bf16x8 bl = *(const bf16x8*)(WTlo + bo);
            acc[0][t] = __builtin_amdgcn_mfma_f32_16x16x32_bf16(ah0, bh, acc[0][t], 0, 0, 0);
            acc[0][t] = __builtin_amdgcn_mfma_f32_16x16x32_bf16(al0, bh, acc[0][t], 0, 0, 0);
            acc[0][t] = __builtin_amdgcn_mfma_f32_16x16x32_bf16(ah0, bl, acc[0][t], 0, 0, 0);
            acc[1][t] = __builtin_amdgcn_mfma_f32_16x16x32_bf16(ah1, bh, acc[1][t], 0, 0, 0);
            acc[1][t] = __builtin_amdgcn_mfma_f32_16x16x32_bf16(al1, bh, acc[1][t], 0, 0, 0);
            acc[1][t] = __builtin_amdgcn_mfma_f32_16x16x32_bf16(ah1, bl, acc[1][t], 0, 0, 0);
        }
    }
#pragma unroll
    for (int rs = 0; rs < 2; ++rs) {
#pragma unroll
        for (int t = 0; t < 16; ++t) {
#pragma unroll
            for (int reg = 0; reg < 4; ++reg) {
                int row = tile + rs * 16 + grp * 4 + reg;
                if (row < M) C[(size_t)row * 256 + t * 16 + n0] = acc[rs][t][reg];
            }
        }
    }
}

// ---------- GCN aggregation (f32 h) ----------
__global__ __launch_bounds__(256) void aggregate_kernel(const float* __restrict__ h,
        const int* __restrict__ indptr, const int* __restrict__ csr_src,
        const float* __restrict__ dinv, const void* __restrict__ bias,
        float* __restrict__ out, int n, int do_relu, const int* __restrict__ flag) {
    int wave = threadIdx.x >> 6;
    int lane = threadIdx.x & 63;
    int v = blockIdx.x * 4 + wave;
    if (v >= n) return;
    int beg = indptr[v];
    int end = indptr[v + 1];
    float dv = dinv[v];
    float4 hv = *(const float4*)(h + (size_t)v * 256 + lane * 4);
    float a0 = dv * hv.x, a1 = dv * hv.y, a2 = dv * hv.z, a3 = dv * hv.w;
    for (int e = beg; e < end; ++e) {
        int s = csr_src[e];
        float w = dinv[s];
        float4 hs = *(const float4*)(h + (size_t)s * 256 + lane * 4);
        a0 += w * hs.x; a1 += w * hs.y; a2 += w * hs.z; a3 += w * hs.w;
    }
    float4 bb;
    if (*flag != 0) {
        bb = *(const float4*)((const float*)bias + lane * 4);
    } else {
        ushort4 bu = *(const ushort4*)((const unsigned short*)bias + lane * 4);
        bb.x = b2f(bu.x); bb.y = b2f(bu.y); bb.z = b2f(bu.z); bb.w = b2f(bu.w);
    }
    float o0 = dv * a0 + bb.x;
    float o1 = dv * a1 + bb.y;
    float o2 = dv * a2 + bb.z;
    float o3 = dv * a3 + bb.w;
    if (do_relu) {
        o0 = fmaxf(o0, 0.f); o1 = fmaxf(o1, 0.f); o2 = fmaxf(o2, 0.f); o3 = fmaxf(o3, 0.f);
    }
    float4 ov = {o0, o1, o2, o3};
    *(float4*)(out + (size_t)v * 256 + lane * 4) = ov;
}

// ---------- edge scoring: sigmoid(dot(h[src], h[dst])) ----------
__global__ __launch_bounds__(256) void edge_score_kernel(const float* __restrict__ h,
        const int* __restrict__ src, const int* __restrict__ dst,
        void* __restrict__ out, int E, const int* __restrict__ flag) {
    int wave = threadIdx.x >> 6;
    int lane = threadIdx.x & 63;
    int e = blockIdx.x * 4 + wave;
    if (e >= E) return;
    int s = src[e], d = dst[e];
    float4 ha = *(const float4*)(h + (size_t)s * 256 + lane * 4);
    float4 hb = *(const float4*)(h + (size_t)d * 256 + lane * 4);
    float p = ha.x * hb.x + ha.y * hb.y + ha.z * hb.z + ha.w * hb.w;
#pragma unroll
    for (int off = 32; off > 0; off >>= 1) p += __shfl_xor(p, off, 64);
    if (lane == 0) {
        float prob = 1.f / (1.f + __expf(-p));
        if (*flag != 0)
            ((float*)out)[e] = prob;
        else
            ((unsigned short*)out)[e] = f2b(prob);
    }
}

extern "C" void kernel_launch(void* const* d_in, const int* in_sizes, int n_in,
                              void* d_out, int out_size, void* d_ws, size_t ws_size,
                              hipStream_t stream) {
    const void* x  = d_in[0];
    const int* edge_index = (const int*)d_in[1];
    const void* W1 = d_in[2];
    const void* b1 = d_in[3];
    const void* W2 = d_in[4];
    const void* b2 = d_in[5];

    const int N = in_sizes[0] / D_IN;   // 50000
    const int E = in_sizes[1] / 2;      // 800000
    const int* src = edge_index;
    const int* dst = edge_index + E;

    char* ws = (char*)d_ws;
    size_t off = 0;
    auto alloc = [&](size_t bytes) {
        char* p = ws + off;
        off = (off + bytes + 255) & ~(size_t)255;
        return p;
    };
    int* flag     = (int*)alloc(256);
    float* dinv   = (float*)alloc((size_t)N * 4);
    int* counts   = (int*)alloc((size_t)N * 4);
    int* indptr   = (int*)alloc((size_t)(N + 1) * 4);
    int* cursor   = (int*)alloc((size_t)N * 4);
    int* csr_src  = (int*)alloc((size_t)E * 4);
    unsigned short* W1Thi = (unsigned short*)alloc((size_t)D_IN * 256 * 2);
    unsigned short* W1Tlo = (unsigned short*)alloc((size_t)D_IN * 256 * 2);
    unsigned short* W2Thi = (unsigned short*)alloc((size_t)D_HID * 256 * 2);
    unsigned short* W2Tlo = (unsigned short*)alloc((size_t)D_HID * 256 * 2);
    float* hA     = (float*)alloc((size_t)N * 256 * 4);   // 51.2 MB
    float* hB     = (float*)alloc((size_t)N * 256 * 4);   // 51.2 MB

    detect_dtype_kernel<<<1, 256, 0, stream>>>((const unsigned short*)x, 65536, flag);
    hipMemsetAsync(counts, 0, (size_t)N * 4, stream);
    hist_kernel<<<(E + 255) / 256, 256, 0, stream>>>(dst, counts, E);
    scan_kernel<<<1, 1024, 0, stream>>>(counts, indptr, cursor, dinv, N);
    scatter_kernel<<<(E + 255) / 256, 256, 0, stream>>>(src, dst, cursor, csr_src, E);
    wsplit_kernel<<<(D_IN * 256 + 255) / 256, 256, 0, stream>>>(W1, W1Thi, W1Tlo, D_IN, flag);
    wsplit_kernel<<<(D_HID * 256 + 255) / 256, 256, 0, stream>>>(W2, W2Thi, W2Tlo, D_HID, flag);

    int ggrid = (N + 127) / 128;
    gemm_mfma_split<D_IN><<<ggrid, 256, 0, stream>>>(x, W1Thi, W1Tlo, hA, N, flag, 0);
    aggregate_kernel<<<(N + 3) / 4, 256, 0, stream>>>(hA, indptr, csr_src, dinv, b1, hB, N, 1, flag);
    gemm_mfma_split<D_HID><<<ggrid, 256, 0, stream>>>(hB, W2Thi, W2Tlo, hA, N, flag, 1);
    aggregate_kernel<<<(N + 3) / 4, 256, 0, stream>>>(hA, indptr, csr_src, dinv, b2, hB, N, 0, flag);
    edge_score_kernel<<<(E + 3) / 4, 256, 0, stream>>>(hB, src, dst, d_out, E, flag);
}

// Round 5
// 1083.518 us; speedup vs baseline: 1.1626x; 1.0002x over previous
//
#include <hip/hip_runtime.h>
#include <stdint.h>

#define D_IN 512
#define D_HID 256

typedef __attribute__((ext_vector_type(8))) short bf16x8;
typedef __attribute__((ext_vector_type(4))) float f32x4;

__device__ __forceinline__ float b2f(unsigned short u) {
    union { float f; uint32_t i; } x; x.i = ((uint32_t)u) << 16; return x.f;
}
__device__ __forceinline__ unsigned short f2b(float f) {
    union { float f; uint32_t i; } x; x.f = f;
    uint32_t i = x.i;
    uint32_t r = (i + 0x7FFFu + ((i >> 16) & 1u)) >> 16;
    return (unsigned short)r;
}

// ---------- dtype detector: flag=1 if raw bits are float32, 0 if bf16 ----------
__global__ void detect_dtype_kernel(const unsigned short* __restrict__ raw, int nscan,
                                    int* __restrict__ flag) {
    __shared__ int any;
    if (threadIdx.x == 0) any = 0;
    __syncthreads();
    int hit = 0;
    for (int i = threadIdx.x; i < nscan; i += blockDim.x) {
        unsigned short u = raw[i];
        if (((u >> 7) & 0xFF) == 0xFF) hit = 1;
    }
    if (hit) atomicAdd(&any, 1);
    __syncthreads();
    if (threadIdx.x == 0) *flag = (any != 0) ? 1 : 0;
}

// ---------- degree histogram / scan / CSR scatter ----------
__global__ void hist_kernel(const int* __restrict__ dst, int* __restrict__ counts, int E) {
    int e = blockIdx.x * blockDim.x + threadIdx.x;
    if (e < E) atomicAdd(&counts[dst[e]], 1);
}

__global__ void scan_kernel(const int* __restrict__ counts, int* __restrict__ indptr,
                            int* __restrict__ cursor, float* __restrict__ dinv, int n) {
    __shared__ int sh[1024];
    __shared__ int carry_s;
    if (threadIdx.x == 0) carry_s = 0;
    __syncthreads();
    int nch = (n + 1023) >> 10;
    for (int c = 0; c < nch; ++c) {
        int i = (c << 10) + threadIdx.x;
        int v = (i < n) ? counts[i] : 0;
        sh[threadIdx.x] = v;
        __syncthreads();
        for (int off = 1; off < 1024; off <<= 1) {
            int t = (threadIdx.x >= off) ? sh[threadIdx.x - off] : 0;
            __syncthreads();
            sh[threadIdx.x] += t;
            __syncthreads();
        }
        int incl = sh[threadIdx.x];
        int base = carry_s;
        __syncthreads();
        if (i < n) {
            int e = base + incl - v;
            indptr[i] = e;
            cursor[i] = e;
            dinv[i] = rsqrtf((float)(v + 1));  // self-loop => deg >= 1 always
        }
        if (threadIdx.x == 1023) carry_s = base + incl;
        __syncthreads();
    }
    if (threadIdx.x == 0) indptr[n] = carry_s;
}

__global__ void scatter_kernel(const int* __restrict__ src, const int* __restrict__ dst,
                               int* __restrict__ cursor, int* __restrict__ csr_src, int E) {
    int e = blockIdx.x * blockDim.x + threadIdx.x;
    if (e < E) {
        int d = dst[e];
        int pos = atomicAdd(&cursor[d], 1);
        csr_src[pos] = src[e];
    }
}

// ---------- W transpose + bf16 hi/lo split: W[K][256] -> WThi/WTlo [256][K] ----------
__global__ void wsplit_kernel(const void* __restrict__ W, unsigned short* __restrict__ WThi,
                              unsigned short* __restrict__ WTlo, int K,
                              const int* __restrict__ flag) {
    int idx = blockIdx.x * blockDim.x + threadIdx.x;
    if (idx >= K * 256) return;
    int k = idx >> 8;
    int n = idx & 255;
    float v = (*flag != 0) ? ((const float*)W)[idx] : b2f(((const unsigned short*)W)[idx]);
    unsigned short h = f2b(v);
    float r = v - b2f(h);
    WThi[n * K + k] = h;
    WTlo[n * K + k] = f2b(r);
}

// ---------- split-bf16 MFMA GEMM: C[M,256] = A[M,K] @ W[K,256], C stored bf16 ----------
// wave: 32 rows x 256 cols. A frag 16B contiguous; B frag contiguous in WT[n][k].
// C/D: col = lane&15, row = (lane>>4)*4 + reg  [measured m89].
// AF32: A is f32 -> split A=Ah+Al, 3 MFMA terms (AhWh+AlWh+AhWl), rel err ~2e-5.
// else: A is bf16 -> 2 terms (AhWh+AhWl).
__device__ __forceinline__ void load_split_f32(const float* p, bf16x8& hi, bf16x8& lo) {
    float4 v0 = *(const float4*)p;
    float4 v1 = *(const float4*)(p + 4);
    float vv[8] = {v0.x, v0.y, v0.z, v0.w, v1.x, v1.y, v1.z, v1.w};
#pragma unroll
    for (int j = 0; j < 8; ++j) {
        unsigned short h = f2b(vv[j]);
        float r = vv[j] - b2f(h);
        hi[j] = (short)h;
        lo[j] = (short)f2b(r);
    }
}

template<int K, bool AF32>
__device__ __forceinline__ void gemm_core(const void* __restrict__ A,
        const unsigned short* __restrict__ WThi, const unsigned short* __restrict__ WTlo,
        unsigned short* __restrict__ C, int M, int tile, int lane) {
    int n0 = lane & 15;
    int grp = lane >> 4;
    const float* A32 = (const float*)A;
    const unsigned short* A16 = (const unsigned short*)A;
    int ra = min(tile + n0, M - 1);
    int rb = min(tile + 16 + n0, M - 1);

    f32x4 acc[2][16];
#pragma unroll
    for (int rs = 0; rs < 2; ++rs)
#pragma unroll
        for (int t = 0; t < 16; ++t) acc[rs][t] = (f32x4){0.f, 0.f, 0.f, 0.f};

    for (int kk = 0; kk < K / 32; ++kk) {
        int kof = kk * 32 + grp * 8;
        bf16x8 ah0, al0, ah1, al1;
        if (AF32) {
            load_split_f32(A32 + (size_t)ra * K + kof, ah0, al0);
            load_split_f32(A32 + (size_t)rb * K + kof, ah1, al1);
        } else {
            ah0 = *(const bf16x8*)(A16 + (size_t)ra * K + kof);
            ah1 = *(const bf16x8*)(A16 + (size_t)rb * K + kof);
        }
#pragma unroll
        for (int t = 0; t < 16; ++t) {
            size_t bo = (size_t)(t * 16 + n0) * K + kof;
            bf16x8 bh = *(const bf16x8*)(WThi + bo);
            bf16x8 bl = *(const bf16x8*)(WTlo + bo);
            acc[0][t] = __builtin_amdgcn_mfma_f32_16x16x32_bf16(ah0, bh, acc[0][t], 0, 0, 0);
            if (AF32)
                acc[0][t] = __builtin_amdgcn_mfma_f32_16x16x32_bf16(al0, bh, acc[0][t], 0, 0, 0);
            acc[0][t] = __builtin_amdgcn_mfma_f32_16x16x32_bf16(ah0, bl, acc[0][t], 0, 0, 0);
            acc[1][t] = __builtin_amdgcn_mfma_f32_16x16x32_bf16(ah1, bh, acc[1][t], 0, 0, 0);
            if (AF32)
                acc[1][t] = __builtin_amdgcn_mfma_f32_16x16x32_bf16(al1, bh, acc[1][t], 0, 0, 0);
            acc[1][t] = __builtin_amdgcn_mfma_f32_16x16x32_bf16(ah1, bl, acc[1][t], 0, 0, 0);
        }
    }
#pragma unroll
    for (int rs = 0; rs < 2; ++rs) {
#pragma unroll
        for (int t = 0; t < 16; ++t) {
#pragma unroll
            for (int reg = 0; reg < 4; ++reg) {
                int row = tile + rs * 16 + grp * 4 + reg;
                if (row < M) C[(size_t)row * 256 + t * 16 + n0] = f2b(acc[rs][t][reg]);
            }
        }
    }
}

// GEMM1: A dtype decided by flag (f32 -> 3-term split; bf16 -> 2-term)
template<int K>
__global__ __launch_bounds__(256) void gemm1_kernel(const void* __restrict__ A,
        const unsigned short* __restrict__ WThi, const unsigned short* __restrict__ WTlo,
        unsigned short* __restrict__ C, int M, const int* __restrict__ flag) {
    int lane = threadIdx.x & 63;
    int tile = blockIdx.x * 128 + (threadIdx.x >> 6) * 32;
    if (tile >= M) return;
    if (*flag != 0)
        gemm_core<K, true>(A, WThi, WTlo, C, M, tile, lane);
    else
        gemm_core<K, false>(A, WThi, WTlo, C, M, tile, lane);
}

// GEMM2: A is bf16 (h buffer)
template<int K>
__global__ __launch_bounds__(256) void gemm2_kernel(const unsigned short* __restrict__ A,
        const unsigned short* __restrict__ WThi, const unsigned short* __restrict__ WTlo,
        unsigned short* __restrict__ C, int M) {
    int lane = threadIdx.x & 63;
    int tile = blockIdx.x * 128 + (threadIdx.x >> 6) * 32;
    if (tile >= M) return;
    gemm_core<K, false>(A, WThi, WTlo, C, M, tile, lane);
}

// ---------- GCN aggregation (bf16 h in, bf16 out, f32 accum) ----------
__global__ __launch_bounds__(256) void aggregate_kernel(const unsigned short* __restrict__ h,
        const int* __restrict__ indptr, const int* __restrict__ csr_src,
        const float* __restrict__ dinv, const void* __restrict__ bias,
        unsigned short* __restrict__ out, int n, int do_relu, const int* __restrict__ flag) {
    int wave = threadIdx.x >> 6;
    int lane = threadIdx.x & 63;
    int v = blockIdx.x * 4 + wave;
    if (v >= n) return;
    int beg = indptr[v];
    int end = indptr[v + 1];
    float dv = dinv[v];
    ushort4 hv = *(const ushort4*)(h + (size_t)v * 256 + lane * 4);
    float a0 = dv * b2f(hv.x), a1 = dv * b2f(hv.y), a2 = dv * b2f(hv.z), a3 = dv * b2f(hv.w);
    for (int e = beg; e < end; ++e) {
        int s = csr_src[e];
        float w = dinv[s];
        ushort4 hs = *(const ushort4*)(h + (size_t)s * 256 + lane * 4);
        a0 += w * b2f(hs.x); a1 += w * b2f(hs.y); a2 += w * b2f(hs.z); a3 += w * b2f(hs.w);
    }
    float4 bb;
    if (*flag != 0) {
        bb = *(const float4*)((const float*)bias + lane * 4);
    } else {
        ushort4 bu = *(const ushort4*)((const unsigned short*)bias + lane * 4);
        bb.x = b2f(bu.x); bb.y = b2f(bu.y); bb.z = b2f(bu.z); bb.w = b2f(bu.w);
    }
    float o0 = dv * a0 + bb.x;
    float o1 = dv * a1 + bb.y;
    float o2 = dv * a2 + bb.z;
    float o3 = dv * a3 + bb.w;
    if (do_relu) {
        o0 = fmaxf(o0, 0.f); o1 = fmaxf(o1, 0.f); o2 = fmaxf(o2, 0.f); o3 = fmaxf(o3, 0.f);
    }
    ushort4 ov;
    ov.x = f2b(o0); ov.y = f2b(o1); ov.z = f2b(o2); ov.w = f2b(o3);
    *(ushort4*)(out + (size_t)v * 256 + lane * 4) = ov;
}

// ---------- edge scoring: sigmoid(dot(h[src], h[dst])), bf16 h ----------
__global__ __launch_bounds__(256) void edge_score_kernel(const unsigned short* __restrict__ h,
        const int* __restrict__ src, const int* __restrict__ dst,
        void* __restrict__ out, int E, const int* __restrict__ flag) {
    int wave = threadIdx.x >> 6;
    int lane = threadIdx.x & 63;
    int e = blockIdx.x * 4 + wave;
    if (e >= E) return;
    int s = src[e], d = dst[e];
    ushort4 ha = *(const ushort4*)(h + (size_t)s * 256 + lane * 4);
    ushort4 hb = *(const ushort4*)(h + (size_t)d * 256 + lane * 4);
    float p = b2f(ha.x) * b2f(hb.x) + b2f(ha.y) * b2f(hb.y) +
              b2f(ha.z) * b2f(hb.z) + b2f(ha.w) * b2f(hb.w);
#pragma unroll
    for (int off = 32; off > 0; off >>= 1) p += __shfl_xor(p, off, 64);
    if (lane == 0) {
        float prob = 1.f / (1.f + __expf(-p));
        if (*flag != 0)
            ((float*)out)[e] = prob;
        else
            ((unsigned short*)out)[e] = f2b(prob);
    }
}

extern "C" void kernel_launch(void* const* d_in, const int* in_sizes, int n_in,
                              void* d_out, int out_size, void* d_ws, size_t ws_size,
                              hipStream_t stream) {
    const void* x  = d_in[0];
    const int* edge_index = (const int*)d_in[1];
    const void* W1 = d_in[2];
    const void* b1 = d_in[3];
    const void* W2 = d_in[4];
    const void* b2 = d_in[5];

    const int N = in_sizes[0] / D_IN;   // 50000
    const int E = in_sizes[1] / 2;      // 800000
    const int* src = edge_index;
    const int* dst = edge_index + E;

    char* ws = (char*)d_ws;
    size_t off = 0;
    auto alloc = [&](size_t bytes) {
        char* p = ws + off;
        off = (off + bytes + 255) & ~(size_t)255;
        return p;
    };
    int* flag     = (int*)alloc(256);
    float* dinv   = (float*)alloc((size_t)N * 4);
    int* counts   = (int*)alloc((size_t)N * 4);
    int* indptr   = (int*)alloc((size_t)(N + 1) * 4);
    int* cursor   = (int*)alloc((size_t)N * 4);
    int* csr_src  = (int*)alloc((size_t)E * 4);
    unsigned short* W1Thi = (unsigned short*)alloc((size_t)D_IN * 256 * 2);
    unsigned short* W1Tlo = (unsigned short*)alloc((size_t)D_IN * 256 * 2);
    unsigned short* W2Thi = (unsigned short*)alloc((size_t)D_HID * 256 * 2);
    unsigned short* W2Tlo = (unsigned short*)alloc((size_t)D_HID * 256 * 2);
    unsigned short* hA = (unsigned short*)alloc((size_t)N * 256 * 2);   // 25.6 MB
    unsigned short* hB = (unsigned short*)alloc((size_t)N * 256 * 2);   // 25.6 MB

    detect_dtype_kernel<<<1, 256, 0, stream>>>((const unsigned short*)x, 65536, flag);
    hipMemsetAsync(counts, 0, (size_t)N * 4, stream);
    hist_kernel<<<(E + 255) / 256, 256, 0, stream>>>(dst, counts, E);
    scan_kernel<<<1, 1024, 0, stream>>>(counts, indptr, cursor, dinv, N);
    scatter_kernel<<<(E + 255) / 256, 256, 0, stream>>>(src, dst, cursor, csr_src, E);
    wsplit_kernel<<<(D_IN * 256 + 255) / 256, 256, 0, stream>>>(W1, W1Thi, W1Tlo, D_IN, flag);
    wsplit_kernel<<<(D_HID * 256 + 255) / 256, 256, 0, stream>>>(W2, W2Thi, W2Tlo, D_HID, flag);

    int ggrid = (N + 127) / 128;
    gemm1_kernel<D_IN><<<ggrid, 256, 0, stream>>>(x, W1Thi, W1Tlo, hA, N, flag);
    aggregate_kernel<<<(N + 3) / 4, 256, 0, stream>>>(hA, indptr, csr_src, dinv, b1, hB, N, 1, flag);
    gemm2_kernel<D_HID><<<ggrid, 256, 0, stream>>>(hB, W2Thi, W2Tlo, hA, N);
    aggregate_kernel<<<(N + 3) / 4, 256, 0, stream>>>(hA, indptr, csr_src, dinv, b2, hB, N, 0, flag);
    edge_score_kernel<<<(E + 3) / 4, 256, 0, stream>>>(hB, src, dst, d_out, E, flag);
}

// Round 6
// 1038.289 us; speedup vs baseline: 1.2133x; 1.0436x over previous
//
#include <hip/hip_runtime.h>
#include <stdint.h>

#define D_IN 512
#define D_HID 256

typedef __attribute__((ext_vector_type(8))) short bf16x8;
typedef __attribute__((ext_vector_type(4))) float f32x4;

__device__ __forceinline__ float b2f(unsigned short u) {
    union { float f; uint32_t i; } x; x.i = ((uint32_t)u) << 16; return x.f;
}
__device__ __forceinline__ unsigned short f2b(float f) {
    union { float f; uint32_t i; } x; x.f = f;
    uint32_t i = x.i;
    uint32_t r = (i + 0x7FFFu + ((i >> 16) & 1u)) >> 16;
    return (unsigned short)r;
}

// ---------- dtype detector: flag=1 if raw bits are float32, 0 if bf16 ----------
__global__ void detect_dtype_kernel(const unsigned short* __restrict__ raw, int nscan,
                                    int* __restrict__ flag) {
    __shared__ int any;
    if (threadIdx.x == 0) any = 0;
    __syncthreads();
    int hit = 0;
    for (int i = threadIdx.x; i < nscan; i += blockDim.x) {
        unsigned short u = raw[i];
        if (((u >> 7) & 0xFF) == 0xFF) hit = 1;
    }
    if (hit) atomicAdd(&any, 1);
    __syncthreads();
    if (threadIdx.x == 0) *flag = (any != 0) ? 1 : 0;
}

// ---------- degree histogram ----------
__global__ void hist_kernel(const int* __restrict__ dst, int* __restrict__ counts, int E) {
    int e = blockIdx.x * blockDim.x + threadIdx.x;
    if (e < E) atomicAdd(&counts[dst[e]], 1);
}

// ---------- parallel scan: P1 block partial sums (1024 elems/block) ----------
__global__ __launch_bounds__(256) void partial_sum_kernel(const int* __restrict__ counts,
        int* __restrict__ partial, int n) {
    __shared__ int sh[4];
    int b = blockIdx.x;
    int lane = threadIdx.x & 63, wv = threadIdx.x >> 6;
    int s = 0;
    for (int j = threadIdx.x; j < 1024; j += 256) {
        int i = b * 1024 + j;
        s += (i < n) ? counts[i] : 0;
    }
#pragma unroll
    for (int off = 32; off > 0; off >>= 1) s += __shfl_down(s, off, 64);
    if (lane == 0) sh[wv] = s;
    __syncthreads();
    if (threadIdx.x == 0) partial[b] = sh[0] + sh[1] + sh[2] + sh[3];
}

// ---------- P2: 1-wave exclusive scan of <=64 partials; writes indptr[N]=total ----------
__global__ void scan_partials_kernel(int* __restrict__ partial, int nb,
                                     int* __restrict__ indptr, int N) {
    int lane = threadIdx.x & 63;
    int orig = (lane < nb) ? partial[lane] : 0;
    int v = orig;
#pragma unroll
    for (int off = 1; off < 64; off <<= 1) {
        int u = __shfl(v, lane - off, 64);
        if (lane >= off) v += u;
    }
    int tot = __shfl(v, nb - 1, 64);
    if (lane < nb) partial[lane] = v - orig;   // exclusive
    if (lane == 0) indptr[N] = tot;
}

// ---------- P3: per-chunk scan + indptr/cursor/dinv ----------
__global__ __launch_bounds__(1024) void scan_chunk_kernel(const int* __restrict__ counts,
        const int* __restrict__ partial, int* __restrict__ indptr, int* __restrict__ cursor,
        float* __restrict__ dinv, int n) {
    __shared__ int sh[1024];
    int b = blockIdx.x;
    int i = b * 1024 + threadIdx.x;
    int v = (i < n) ? counts[i] : 0;
    sh[threadIdx.x] = v;
    __syncthreads();
    for (int off = 1; off < 1024; off <<= 1) {
        int t = (threadIdx.x >= off) ? sh[threadIdx.x - off] : 0;
        __syncthreads();
        sh[threadIdx.x] += t;
        __syncthreads();
    }
    if (i < n) {
        int e = partial[b] + sh[threadIdx.x] - v;
        indptr[i] = e;
        cursor[i] = e;
        dinv[i] = rsqrtf((float)(v + 1));   // self-loop => deg >= 1
    }
}

__global__ void scatter_kernel(const int* __restrict__ src, const int* __restrict__ dst,
                               int* __restrict__ cursor, int* __restrict__ csr_src, int E) {
    int e = blockIdx.x * blockDim.x + threadIdx.x;
    if (e < E) {
        int d = dst[e];
        int pos = atomicAdd(&cursor[d], 1);
        csr_src[pos] = src[e];
    }
}

// ---------- W transpose + bf16 hi/lo split: W[K][256] -> WThi/WTlo [256][K] ----------
__global__ void wsplit_kernel(const void* __restrict__ W, unsigned short* __restrict__ WThi,
                              unsigned short* __restrict__ WTlo, int K,
                              const int* __restrict__ flag) {
    int idx = blockIdx.x * blockDim.x + threadIdx.x;
    if (idx >= K * 256) return;
    int k = idx >> 8;
    int n = idx & 255;
    float v = (*flag != 0) ? ((const float*)W)[idx] : b2f(((const unsigned short*)W)[idx]);
    unsigned short h = f2b(v);
    float r = v - b2f(h);
    WThi[n * K + k] = h;
    WTlo[n * K + k] = f2b(r);
}

// ---------- LDS-staged split-bf16 MFMA GEMM: C[M,256] = A[M,K] @ W[K,256] ----------
// block = 256 thr / 4 waves; tile 64 rows x 256 cols; wave = 16 rows x 256 cols.
// Per k-chunk(32): stage A[64][32] -> LDS as hi/lo bf16 (stride 40 ushort = 80B, 16B-aligned,
// <=2-way banks). Fragments: A from ds_read_b128; W hi/lo stream from L1/L2.
// C/D: col = lane&15, row = (lane>>4)*4 + reg  [measured m89].
// AF32: 3 MFMA terms (AhWh+AlWh+AhWl), rel err ~2e-5. bf16 A: 2 terms.
#define ASTRIDE 40
template<int K, bool AF32>
__device__ __forceinline__ void gemm_loop(const void* __restrict__ A,
        const unsigned short* __restrict__ WThi, const unsigned short* __restrict__ WTlo,
        unsigned short* __restrict__ C, int M,
        unsigned short* Ahi, unsigned short* Alo) {
    const float* A32 = (const float*)A;
    const unsigned short* A16 = (const unsigned short*)A;
    int t = threadIdx.x;
    int lane = t & 63, wv = t >> 6;
    int n0 = lane & 15, grp = lane >> 4;
    int row0 = blockIdx.x * 64;
    int srow = min(row0 + (t >> 2), M - 1);   // staging: 4 threads/row
    int sseg = (t & 3) * 8;                    // 8 elems each
    int ldsrow = wv * 16 + n0;                 // fragment LDS row

    f32x4 acc[16];
#pragma unroll
    for (int i = 0; i < 16; ++i) acc[i] = (f32x4){0.f, 0.f, 0.f, 0.f};

    for (int kk = 0; kk < K / 32; ++kk) {
        int kof = kk * 32;
        // ---- stage A[64][32] into LDS ----
        if (AF32) {
            const float* p = A32 + (size_t)srow * K + kof + sseg;
            float4 v0 = *(const float4*)p;
            float4 v1 = *(const float4*)(p + 4);
            float vv[8] = {v0.x, v0.y, v0.z, v0.w, v1.x, v1.y, v1.z, v1.w};
            bf16x8 hv, lv;
#pragma unroll
            for (int j = 0; j < 8; ++j) {
                unsigned short h = f2b(vv[j]);
                float r = vv[j] - b2f(h);
                hv[j] = (short)h;
                lv[j] = (short)f2b(r);
            }
            *(bf16x8*)(Ahi + (t >> 2) * ASTRIDE + sseg) = hv;
            *(bf16x8*)(Alo + (t >> 2) * ASTRIDE + sseg) = lv;
        } else {
            bf16x8 u = *(const bf16x8*)(A16 + (size_t)srow * K + kof + sseg);
            *(bf16x8*)(Ahi + (t >> 2) * ASTRIDE + sseg) = u;
        }
        __syncthreads();
        // ---- fragments + MFMA ----
        bf16x8 ah = *(const bf16x8*)(Ahi + ldsrow * ASTRIDE + grp * 8);
        bf16x8 al;
        if (AF32) al = *(const bf16x8*)(Alo + ldsrow * ASTRIDE + grp * 8);
        int kfrag = kof + grp * 8;
#pragma unroll
        for (int ct = 0; ct < 16; ++ct) {
            size_t bo = (size_t)(ct * 16 + n0) * K + kfrag;
            bf16x8 bh = *(const bf16x8*)(WThi + bo);
            bf16x8 bl = *(const bf16x8*)(WTlo + bo);
            acc[ct] = __builtin_amdgcn_mfma_f32_16x16x32_bf16(ah, bh, acc[ct], 0, 0, 0);
            if (AF32)
                acc[ct] = __builtin_amdgcn_mfma_f32_16x16x32_bf16(al, bh, acc[ct], 0, 0, 0);
            acc[ct] = __builtin_amdgcn_mfma_f32_16x16x32_bf16(ah, bl, acc[ct], 0, 0, 0);
        }
        __syncthreads();
    }
    int rbase = row0 + wv * 16 + grp * 4;
#pragma unroll
    for (int ct = 0; ct < 16; ++ct) {
#pragma unroll
        for (int reg = 0; reg < 4; ++reg) {
            int row = rbase + reg;
            if (row < M) C[(size_t)row * 256 + ct * 16 + n0] = f2b(acc[ct][reg]);
        }
    }
}

template<int K>
__global__ __launch_bounds__(256) void gemm_tiled(const void* __restrict__ A,
        const unsigned short* __restrict__ WThi, const unsigned short* __restrict__ WTlo,
        unsigned short* __restrict__ C, int M, const int* __restrict__ flag, int a_is_bf16) {
    __shared__ unsigned short Ahi[64 * ASTRIDE];
    __shared__ unsigned short Alo[64 * ASTRIDE];
    bool af32 = (!a_is_bf16) && (*flag != 0);
    if (af32)
        gemm_loop<K, true>(A, WThi, WTlo, C, M, Ahi, Alo);
    else
        gemm_loop<K, false>(A, WThi, WTlo, C, M, Ahi, Alo);
}

// ---------- GCN aggregation (bf16 h in, bf16 out, f32 accum) ----------
__global__ __launch_bounds__(256) void aggregate_kernel(const unsigned short* __restrict__ h,
        const int* __restrict__ indptr, const int* __restrict__ csr_src,
        const float* __restrict__ dinv, const void* __restrict__ bias,
        unsigned short* __restrict__ out, int n, int do_relu, const int* __restrict__ flag) {
    int wave = threadIdx.x >> 6;
    int lane = threadIdx.x & 63;
    int v = blockIdx.x * 4 + wave;
    if (v >= n) return;
    int beg = indptr[v];
    int end = indptr[v + 1];
    float dv = dinv[v];
    ushort4 hv = *(const ushort4*)(h + (size_t)v * 256 + lane * 4);
    float a0 = dv * b2f(hv.x), a1 = dv * b2f(hv.y), a2 = dv * b2f(hv.z), a3 = dv * b2f(hv.w);
    for (int e = beg; e < end; ++e) {
        int s = csr_src[e];
        float w = dinv[s];
        ushort4 hs = *(const ushort4*)(h + (size_t)s * 256 + lane * 4);
        a0 += w * b2f(hs.x); a1 += w * b2f(hs.y); a2 += w * b2f(hs.z); a3 += w * b2f(hs.w);
    }
    float4 bb;
    if (*flag != 0) {
        bb = *(const float4*)((const float*)bias + lane * 4);
    } else {
        ushort4 bu = *(const ushort4*)((const unsigned short*)bias + lane * 4);
        bb.x = b2f(bu.x); bb.y = b2f(bu.y); bb.z = b2f(bu.z); bb.w = b2f(bu.w);
    }
    float o0 = dv * a0 + bb.x;
    float o1 = dv * a1 + bb.y;
    float o2 = dv * a2 + bb.z;
    float o3 = dv * a3 + bb.w;
    if (do_relu) {
        o0 = fmaxf(o0, 0.f); o1 = fmaxf(o1, 0.f); o2 = fmaxf(o2, 0.f); o3 = fmaxf(o3, 0.f);
    }
    ushort4 ov;
    ov.x = f2b(o0); ov.y = f2b(o1); ov.z = f2b(o2); ov.w = f2b(o3);
    *(ushort4*)(out + (size_t)v * 256 + lane * 4) = ov;
}

// ---------- edge scoring: sigmoid(dot(h[src], h[dst])), bf16 h ----------
__global__ __launch_bounds__(256) void edge_score_kernel(const unsigned short* __restrict__ h,
        const int* __restrict__ src, const int* __restrict__ dst,
        void* __restrict__ out, int E, const int* __restrict__ flag) {
    int wave = threadIdx.x >> 6;
    int lane = threadIdx.x & 63;
    int e = blockIdx.x * 4 + wave;
    if (e >= E) return;
    int s = src[e], d = dst[e];
    ushort4 ha = *(const ushort4*)(h + (size_t)s * 256 + lane * 4);
    ushort4 hb = *(const ushort4*)(h + (size_t)d * 256 + lane * 4);
    float p = b2f(ha.x) * b2f(hb.x) + b2f(ha.y) * b2f(hb.y) +
              b2f(ha.z) * b2f(hb.z) + b2f(ha.w) * b2f(hb.w);
#pragma unroll
    for (int off = 32; off > 0; off >>= 1) p += __shfl_xor(p, off, 64);
    if (lane == 0) {
        float prob = 1.f / (1.f + __expf(-p));
        if (*flag != 0)
            ((float*)out)[e] = prob;
        else
            ((unsigned short*)out)[e] = f2b(prob);
    }
}

extern "C" void kernel_launch(void* const* d_in, const int* in_sizes, int n_in,
                              void* d_out, int out_size, void* d_ws, size_t ws_size,
                              hipStream_t stream) {
    const void* x  = d_in[0];
    const int* edge_index = (const int*)d_in[1];
    const void* W1 = d_in[2];
    const void* b1 = d_in[3];
    const void* W2 = d_in[4];
    const void* b2 = d_in[5];

    const int N = in_sizes[0] / D_IN;   // 50000
    const int E = in_sizes[1] / 2;      // 800000
    const int* src = edge_index;
    const int* dst = edge_index + E;

    char* ws = (char*)d_ws;
    size_t off = 0;
    auto alloc = [&](size_t bytes) {
        char* p = ws + off;
        off = (off + bytes + 255) & ~(size_t)255;
        return p;
    };
    int* flag     = (int*)alloc(256);
    float* dinv   = (float*)alloc((size_t)N * 4);
    int* counts   = (int*)alloc((size_t)N * 4);
    int* indptr   = (int*)alloc((size_t)(N + 1) * 4);
    int* cursor   = (int*)alloc((size_t)N * 4);
    int* partial  = (int*)alloc(64 * 4);
    int* csr_src  = (int*)alloc((size_t)E * 4);
    unsigned short* W1Thi = (unsigned short*)alloc((size_t)D_IN * 256 * 2);
    unsigned short* W1Tlo = (unsigned short*)alloc((size_t)D_IN * 256 * 2);
    unsigned short* W2Thi = (unsigned short*)alloc((size_t)D_HID * 256 * 2);
    unsigned short* W2Tlo = (unsigned short*)alloc((size_t)D_HID * 256 * 2);
    unsigned short* hA = (unsigned short*)alloc((size_t)N * 256 * 2);   // 25.6 MB
    unsigned short* hB = (unsigned short*)alloc((size_t)N * 256 * 2);   // 25.6 MB

    const int nb = (N + 1023) / 1024;   // 49 <= 64

    detect_dtype_kernel<<<1, 256, 0, stream>>>((const unsigned short*)x, 65536, flag);
    hipMemsetAsync(counts, 0, (size_t)N * 4, stream);
    hist_kernel<<<(E + 255) / 256, 256, 0, stream>>>(dst, counts, E);
    partial_sum_kernel<<<nb, 256, 0, stream>>>(counts, partial, N);
    scan_partials_kernel<<<1, 64, 0, stream>>>(partial, nb, indptr, N);
    scan_chunk_kernel<<<nb, 1024, 0, stream>>>(counts, partial, indptr, cursor, dinv, N);
    scatter_kernel<<<(E + 255) / 256, 256, 0, stream>>>(src, dst, cursor, csr_src, E);
    wsplit_kernel<<<(D_IN * 256 + 255) / 256, 256, 0, stream>>>(W1, W1Thi, W1Tlo, D_IN, flag);
    wsplit_kernel<<<(D_HID * 256 + 255) / 256, 256, 0, stream>>>(W2, W2Thi, W2Tlo, D_HID, flag);

    int ggrid = (N + 63) / 64;
    gemm_tiled<D_IN><<<ggrid, 256, 0, stream>>>(x, W1Thi, W1Tlo, hA, N, flag, 0);
    aggregate_kernel<<<(N + 3) / 4, 256, 0, stream>>>(hA, indptr, csr_src, dinv, b1, hB, N, 1, flag);
    gemm_tiled<D_HID><<<ggrid, 256, 0, stream>>>(hB, W2Thi, W2Tlo, hA, N, flag, 1);
    aggregate_kernel<<<(N + 3) / 4, 256, 0, stream>>>(hA, indptr, csr_src, dinv, b2, hB, N, 0, flag);
    edge_score_kernel<<<(E + 3) / 4, 256, 0, stream>>>(hB, src, dst, d_out, E, flag);
}

// Round 7
// 796.172 us; speedup vs baseline: 1.5822x; 1.3041x over previous
//
#include <hip/hip_runtime.h>
#include <stdint.h>

#define D_IN 512
#define D_HID 256

typedef __attribute__((ext_vector_type(8))) short bf16x8;
typedef __attribute__((ext_vector_type(4))) float f32x4;

__device__ __forceinline__ float b2f(unsigned short u) {
    union { float f; uint32_t i; } x; x.i = ((uint32_t)u) << 16; return x.f;
}
__device__ __forceinline__ unsigned short f2b(float f) {
    union { float f; uint32_t i; } x; x.f = f;
    uint32_t i = x.i;
    uint32_t r = (i + 0x7FFFu + ((i >> 16) & 1u)) >> 16;
    return (unsigned short)r;
}

// ---------- dtype detector: flag=1 if raw bits are float32, 0 if bf16 ----------
__global__ void detect_dtype_kernel(const unsigned short* __restrict__ raw, int nscan,
                                    int* __restrict__ flag) {
    __shared__ int any;
    if (threadIdx.x == 0) any = 0;
    __syncthreads();
    int hit = 0;
    for (int i = threadIdx.x; i < nscan; i += blockDim.x) {
        unsigned short u = raw[i];
        if (((u >> 7) & 0xFF) == 0xFF) hit = 1;
    }
    if (hit) atomicAdd(&any, 1);
    __syncthreads();
    if (threadIdx.x == 0) *flag = (any != 0) ? 1 : 0;
}

// ---------- degree histogram ----------
__global__ void hist_kernel(const int* __restrict__ dst, int* __restrict__ counts, int E) {
    int e = blockIdx.x * blockDim.x + threadIdx.x;
    if (e < E) atomicAdd(&counts[dst[e]], 1);
}

// ---------- parallel scan: P1 block partial sums (1024 elems/block) ----------
__global__ __launch_bounds__(256) void partial_sum_kernel(const int* __restrict__ counts,
        int* __restrict__ partial, int n) {
    __shared__ int sh[4];
    int b = blockIdx.x;
    int lane = threadIdx.x & 63, wv = threadIdx.x >> 6;
    int s = 0;
    for (int j = threadIdx.x; j < 1024; j += 256) {
        int i = b * 1024 + j;
        s += (i < n) ? counts[i] : 0;
    }
#pragma unroll
    for (int off = 32; off > 0; off >>= 1) s += __shfl_down(s, off, 64);
    if (lane == 0) sh[wv] = s;
    __syncthreads();
    if (threadIdx.x == 0) partial[b] = sh[0] + sh[1] + sh[2] + sh[3];
}

// ---------- P2: 1-wave exclusive scan of <=64 partials; writes indptr[N]=total ----------
__global__ void scan_partials_kernel(int* __restrict__ partial, int nb,
                                     int* __restrict__ indptr, int N) {
    int lane = threadIdx.x & 63;
    int orig = (lane < nb) ? partial[lane] : 0;
    int v = orig;
#pragma unroll
    for (int off = 1; off < 64; off <<= 1) {
        int u = __shfl(v, lane - off, 64);
        if (lane >= off) v += u;
    }
    int tot = __shfl(v, nb - 1, 64);
    if (lane < nb) partial[lane] = v - orig;   // exclusive
    if (lane == 0) indptr[N] = tot;
}

// ---------- P3: per-chunk scan + indptr/cursor/dinv ----------
__global__ __launch_bounds__(1024) void scan_chunk_kernel(const int* __restrict__ counts,
        const int* __restrict__ partial, int* __restrict__ indptr, int* __restrict__ cursor,
        float* __restrict__ dinv, int n) {
    __shared__ int sh[1024];
    int b = blockIdx.x;
    int i = b * 1024 + threadIdx.x;
    int v = (i < n) ? counts[i] : 0;
    sh[threadIdx.x] = v;
    __syncthreads();
    for (int off = 1; off < 1024; off <<= 1) {
        int t = (threadIdx.x >= off) ? sh[threadIdx.x - off] : 0;
        __syncthreads();
        sh[threadIdx.x] += t;
        __syncthreads();
    }
    if (i < n) {
        int e = partial[b] + sh[threadIdx.x] - v;
        indptr[i] = e;
        cursor[i] = e;
        dinv[i] = rsqrtf((float)(v + 1));   // self-loop => deg >= 1
    }
}

__global__ void scatter_kernel(const int* __restrict__ src, const int* __restrict__ dst,
                               int* __restrict__ cursor, int* __restrict__ csr_src, int E) {
    int e = blockIdx.x * blockDim.x + threadIdx.x;
    if (e < E) {
        int d = dst[e];
        int pos = atomicAdd(&cursor[d], 1);
        csr_src[pos] = src[e];
    }
}

// ---------- W transpose + bf16 hi/lo split: W[K][256] -> WThi/WTlo [256][K] ----------
__global__ void wsplit_kernel(const void* __restrict__ W, unsigned short* __restrict__ WThi,
                              unsigned short* __restrict__ WTlo, int K,
                              const int* __restrict__ flag) {
    int idx = blockIdx.x * blockDim.x + threadIdx.x;
    if (idx >= K * 256) return;
    int k = idx >> 8;
    int n = idx & 255;
    float v = (*flag != 0) ? ((const float*)W)[idx] : b2f(((const unsigned short*)W)[idx]);
    unsigned short h = f2b(v);
    float r = v - b2f(h);
    WThi[n * K + k] = h;
    WTlo[n * K + k] = f2b(r);
}

// ---------- LDS-staged split-bf16 MFMA GEMM: C[M,256] = A[M,K] @ W[K,256] ----------
// block = 256 thr / 4 waves; tile 64 rows x 256 cols.
// COLUMN-PARTITIONED: wave w computes all 64 rows x cols [64w,64w+64) (4 col-tiles).
// -> per k-chunk each lane loads only 8 W fragments (pipelinable), and block-level
//    W traffic is 512 KB (vs 2 MB when every wave read the whole WT).
// A[64][32] staged in LDS as hi/lo bf16 (stride 40 ushort: 16B-aligned, 2-way banks = free).
// C/D: col = lane&15, row = (lane>>4)*4 + reg  [measured m89].
// AF32: 3 MFMA terms (AhWh+AlWh+AhWl), rel err ~2e-5. bf16 A: 2 terms.
#define ASTRIDE 40
template<int K, bool AF32>
__device__ __forceinline__ void gemm_loop(const void* __restrict__ A,
        const unsigned short* __restrict__ WThi, const unsigned short* __restrict__ WTlo,
        unsigned short* __restrict__ C, int M,
        unsigned short* Ahi, unsigned short* Alo) {
    const float* A32 = (const float*)A;
    const unsigned short* A16 = (const unsigned short*)A;
    int t = threadIdx.x;
    int lane = t & 63, wv = t >> 6;
    int n0 = lane & 15, grp = lane >> 4;
    int row0 = blockIdx.x * 64;
    int srow = min(row0 + (t >> 2), M - 1);   // staging: 4 threads/row
    int sseg = (t & 3) * 8;                    // 8 elems each

    f32x4 acc[4][4];                           // [row-tile][col-tile]
#pragma unroll
    for (int rt = 0; rt < 4; ++rt)
#pragma unroll
        for (int j = 0; j < 4; ++j) acc[rt][j] = (f32x4){0.f, 0.f, 0.f, 0.f};

    for (int kk = 0; kk < K / 32; ++kk) {
        int kof = kk * 32;
        // ---- stage A[64][32] into LDS ----
        if (AF32) {
            const float* p = A32 + (size_t)srow * K + kof + sseg;
            float4 v0 = *(const float4*)p;
            float4 v1 = *(const float4*)(p + 4);
            float vv[8] = {v0.x, v0.y, v0.z, v0.w, v1.x, v1.y, v1.z, v1.w};
            bf16x8 hv, lv;
#pragma unroll
            for (int j = 0; j < 8; ++j) {
                unsigned short h = f2b(vv[j]);
                float r = vv[j] - b2f(h);
                hv[j] = (short)h;
                lv[j] = (short)f2b(r);
            }
            *(bf16x8*)(Ahi + (t >> 2) * ASTRIDE + sseg) = hv;
            *(bf16x8*)(Alo + (t >> 2) * ASTRIDE + sseg) = lv;
        } else {
            bf16x8 u = *(const bf16x8*)(A16 + (size_t)srow * K + kof + sseg);
            *(bf16x8*)(Ahi + (t >> 2) * ASTRIDE + sseg) = u;
        }
        __syncthreads();
        int kfrag = kof + grp * 8;
        // ---- W fragments for this wave's 4 col-tiles (issue all loads first) ----
        bf16x8 bh[4], bl[4];
#pragma unroll
        for (int j = 0; j < 4; ++j) {
            int ct = wv * 4 + j;
            size_t bo = (size_t)(ct * 16 + n0) * K + kfrag;
            bh[j] = *(const bf16x8*)(WThi + bo);
            bl[j] = *(const bf16x8*)(WTlo + bo);
        }
        // ---- A fragments (LDS) + MFMA ----
#pragma unroll
        for (int rt = 0; rt < 4; ++rt) {
            bf16x8 ah = *(const bf16x8*)(Ahi + (rt * 16 + n0) * ASTRIDE + grp * 8);
            bf16x8 al;
            if (AF32) al = *(const bf16x8*)(Alo + (rt * 16 + n0) * ASTRIDE + grp * 8);
#pragma unroll
            for (int j = 0; j < 4; ++j) {
                acc[rt][j] = __builtin_amdgcn_mfma_f32_16x16x32_bf16(ah, bh[j], acc[rt][j], 0, 0, 0);
                if (AF32)
                    acc[rt][j] = __builtin_amdgcn_mfma_f32_16x16x32_bf16(al, bh[j], acc[rt][j], 0, 0, 0);
                acc[rt][j] = __builtin_amdgcn_mfma_f32_16x16x32_bf16(ah, bl[j], acc[rt][j], 0, 0, 0);
            }
        }
        __syncthreads();
    }
    // ---- epilogue: row = row0 + rt*16 + grp*4 + reg, col = (wv*4+j)*16 + n0 ----
#pragma unroll
    for (int rt = 0; rt < 4; ++rt) {
#pragma unroll
        for (int j = 0; j < 4; ++j) {
#pragma unroll
            for (int reg = 0; reg < 4; ++reg) {
                int row = row0 + rt * 16 + grp * 4 + reg;
                if (row < M)
                    C[(size_t)row * 256 + (wv * 4 + j) * 16 + n0] = f2b(acc[rt][j][reg]);
            }
        }
    }
}

template<int K>
__global__ __launch_bounds__(256) void gemm_tiled(const void* __restrict__ A,
        const unsigned short* __restrict__ WThi, const unsigned short* __restrict__ WTlo,
        unsigned short* __restrict__ C, int M, const int* __restrict__ flag, int a_is_bf16) {
    __shared__ unsigned short Ahi[64 * ASTRIDE];
    __shared__ unsigned short Alo[64 * ASTRIDE];
    bool af32 = (!a_is_bf16) && (*flag != 0);
    if (af32)
        gemm_loop<K, true>(A, WThi, WTlo, C, M, Ahi, Alo);
    else
        gemm_loop<K, false>(A, WThi, WTlo, C, M, Ahi, Alo);
}

// ---------- GCN aggregation (bf16 h in, bf16 out, f32 accum) ----------
__global__ __launch_bounds__(256) void aggregate_kernel(const unsigned short* __restrict__ h,
        const int* __restrict__ indptr, const int* __restrict__ csr_src,
        const float* __restrict__ dinv, const void* __restrict__ bias,
        unsigned short* __restrict__ out, int n, int do_relu, const int* __restrict__ flag) {
    int wave = threadIdx.x >> 6;
    int lane = threadIdx.x & 63;
    int v = blockIdx.x * 4 + wave;
    if (v >= n) return;
    int beg = indptr[v];
    int end = indptr[v + 1];
    float dv = dinv[v];
    ushort4 hv = *(const ushort4*)(h + (size_t)v * 256 + lane * 4);
    float a0 = dv * b2f(hv.x), a1 = dv * b2f(hv.y), a2 = dv * b2f(hv.z), a3 = dv * b2f(hv.w);
    for (int e = beg; e < end; ++e) {
        int s = csr_src[e];
        float w = dinv[s];
        ushort4 hs = *(const ushort4*)(h + (size_t)s * 256 + lane * 4);
        a0 += w * b2f(hs.x); a1 += w * b2f(hs.y); a2 += w * b2f(hs.z); a3 += w * b2f(hs.w);
    }
    float4 bb;
    if (*flag != 0) {
        bb = *(const float4*)((const float*)bias + lane * 4);
    } else {
        ushort4 bu = *(const ushort4*)((const unsigned short*)bias + lane * 4);
        bb.x = b2f(bu.x); bb.y = b2f(bu.y); bb.z = b2f(bu.z); bb.w = b2f(bu.w);
    }
    float o0 = dv * a0 + bb.x;
    float o1 = dv * a1 + bb.y;
    float o2 = dv * a2 + bb.z;
    float o3 = dv * a3 + bb.w;
    if (do_relu) {
        o0 = fmaxf(o0, 0.f); o1 = fmaxf(o1, 0.f); o2 = fmaxf(o2, 0.f); o3 = fmaxf(o3, 0.f);
    }
    ushort4 ov;
    ov.x = f2b(o0); ov.y = f2b(o1); ov.z = f2b(o2); ov.w = f2b(o3);
    *(ushort4*)(out + (size_t)v * 256 + lane * 4) = ov;
}

// ---------- edge scoring: sigmoid(dot(h[src], h[dst])), bf16 h ----------
__global__ __launch_bounds__(256) void edge_score_kernel(const unsigned short* __restrict__ h,
        const int* __restrict__ src, const int* __restrict__ dst,
        void* __restrict__ out, int E, const int* __restrict__ flag) {
    int wave = threadIdx.x >> 6;
    int lane = threadIdx.x & 63;
    int e = blockIdx.x * 4 + wave;
    if (e >= E) return;
    int s = src[e], d = dst[e];
    ushort4 ha = *(const ushort4*)(h + (size_t)s * 256 + lane * 4);
    ushort4 hb = *(const ushort4*)(h + (size_t)d * 256 + lane * 4);
    float p = b2f(ha.x) * b2f(hb.x) + b2f(ha.y) * b2f(hb.y) +
              b2f(ha.z) * b2f(hb.z) + b2f(ha.w) * b2f(hb.w);
#pragma unroll
    for (int off = 32; off > 0; off >>= 1) p += __shfl_xor(p, off, 64);
    if (lane == 0) {
        float prob = 1.f / (1.f + __expf(-p));
        if (*flag != 0)
            ((float*)out)[e] = prob;
        else
            ((unsigned short*)out)[e] = f2b(prob);
    }
}

extern "C" void kernel_launch(void* const* d_in, const int* in_sizes, int n_in,
                              void* d_out, int out_size, void* d_ws, size_t ws_size,
                              hipStream_t stream) {
    const void* x  = d_in[0];
    const int* edge_index = (const int*)d_in[1];
    const void* W1 = d_in[2];
    const void* b1 = d_in[3];
    const void* W2 = d_in[4];
    const void* b2 = d_in[5];

    const int N = in_sizes[0] / D_IN;   // 50000
    const int E = in_sizes[1] / 2;      // 800000
    const int* src = edge_index;
    const int* dst = edge_index + E;

    char* ws = (char*)d_ws;
    size_t off = 0;
    auto alloc = [&](size_t bytes) {
        char* p = ws + off;
        off = (off + bytes + 255) & ~(size_t)255;
        return p;
    };
    int* flag     = (int*)alloc(256);
    float* dinv   = (float*)alloc((size_t)N * 4);
    int* counts   = (int*)alloc((size_t)N * 4);
    int* indptr   = (int*)alloc((size_t)(N + 1) * 4);
    int* cursor   = (int*)alloc((size_t)N * 4);
    int* partial  = (int*)alloc(64 * 4);
    int* csr_src  = (int*)alloc((size_t)E * 4);
    unsigned short* W1Thi = (unsigned short*)alloc((size_t)D_IN * 256 * 2);
    unsigned short* W1Tlo = (unsigned short*)alloc((size_t)D_IN * 256 * 2);
    unsigned short* W2Thi = (unsigned short*)alloc((size_t)D_HID * 256 * 2);
    unsigned short* W2Tlo = (unsigned short*)alloc((size_t)D_HID * 256 * 2);
    unsigned short* hA = (unsigned short*)alloc((size_t)N * 256 * 2);   // 25.6 MB
    unsigned short* hB = (unsigned short*)alloc((size_t)N * 256 * 2);   // 25.6 MB

    const int nb = (N + 1023) / 1024;   // 49 <= 64

    detect_dtype_kernel<<<1, 256, 0, stream>>>((const unsigned short*)x, 65536, flag);
    hipMemsetAsync(counts, 0, (size_t)N * 4, stream);
    hist_kernel<<<(E + 255) / 256, 256, 0, stream>>>(dst, counts, E);
    partial_sum_kernel<<<nb, 256, 0, stream>>>(counts, partial, N);
    scan_partials_kernel<<<1, 64, 0, stream>>>(partial, nb, indptr, N);
    scan_chunk_kernel<<<nb, 1024, 0, stream>>>(counts, partial, indptr, cursor, dinv, N);
    scatter_kernel<<<(E + 255) / 256, 256, 0, stream>>>(src, dst, cursor, csr_src, E);
    wsplit_kernel<<<(D_IN * 256 + 255) / 256, 256, 0, stream>>>(W1, W1Thi, W1Tlo, D_IN, flag);
    wsplit_kernel<<<(D_HID * 256 + 255) / 256, 256, 0, stream>>>(W2, W2Thi, W2Tlo, D_HID, flag);

    int ggrid = (N + 63) / 64;
    gemm_tiled<D_IN><<<ggrid, 256, 0, stream>>>(x, W1Thi, W1Tlo, hA, N, flag, 0);
    aggregate_kernel<<<(N + 3) / 4, 256, 0, stream>>>(hA, indptr, csr_src, dinv, b1, hB, N, 1, flag);
    gemm_tiled<D_HID><<<ggrid, 256, 0, stream>>>(hB, W2Thi, W2Tlo, hA, N, flag, 1);
    aggregate_kernel<<<(N + 3) / 4, 256, 0, stream>>>(hA, indptr, csr_src, dinv, b2, hB, N, 0, flag);
    edge_score_kernel<<<(E + 3) / 4, 256, 0, stream>>>(hB, src, dst, d_out, E, flag);
}

// Round 8
// 740.827 us; speedup vs baseline: 1.7004x; 1.0747x over previous
//
#include <hip/hip_runtime.h>
#include <stdint.h>

#define D_IN 512
#define D_HID 256

typedef __attribute__((ext_vector_type(8))) short bf16x8;
typedef __attribute__((ext_vector_type(4))) float f32x4;

__device__ __forceinline__ float b2f(unsigned short u) {
    union { float f; uint32_t i; } x; x.i = ((uint32_t)u) << 16; return x.f;
}
__device__ __forceinline__ unsigned short f2b(float f) {
    union { float f; uint32_t i; } x; x.f = f;
    uint32_t i = x.i;
    uint32_t r = (i + 0x7FFFu + ((i >> 16) & 1u)) >> 16;
    return (unsigned short)r;
}

// ---------- dtype detector: flag=1 if raw bits are float32, 0 if bf16 ----------
__global__ void detect_dtype_kernel(const unsigned short* __restrict__ raw, int nscan,
                                    int* __restrict__ flag) {
    __shared__ int any;
    if (threadIdx.x == 0) any = 0;
    __syncthreads();
    int hit = 0;
    for (int i = threadIdx.x; i < nscan; i += blockDim.x) {
        unsigned short u = raw[i];
        if (((u >> 7) & 0xFF) == 0xFF) hit = 1;
    }
    if (hit) atomicAdd(&any, 1);
    __syncthreads();
    if (threadIdx.x == 0) *flag = (any != 0) ? 1 : 0;
}

// ---------- degree histogram ----------
__global__ void hist_kernel(const int* __restrict__ dst, int* __restrict__ counts, int E) {
    int e = blockIdx.x * blockDim.x + threadIdx.x;
    if (e < E) atomicAdd(&counts[dst[e]], 1);
}

// ---------- parallel scan: P1 block partial sums (1024 elems/block) ----------
__global__ __launch_bounds__(256) void partial_sum_kernel(const int* __restrict__ counts,
        int* __restrict__ partial, int n) {
    __shared__ int sh[4];
    int b = blockIdx.x;
    int lane = threadIdx.x & 63, wv = threadIdx.x >> 6;
    int s = 0;
    for (int j = threadIdx.x; j < 1024; j += 256) {
        int i = b * 1024 + j;
        s += (i < n) ? counts[i] : 0;
    }
#pragma unroll
    for (int off = 32; off > 0; off >>= 1) s += __shfl_down(s, off, 64);
    if (lane == 0) sh[wv] = s;
    __syncthreads();
    if (threadIdx.x == 0) partial[b] = sh[0] + sh[1] + sh[2] + sh[3];
}

// ---------- P2: 1-wave exclusive scan of <=64 partials; writes indptr[N]=total ----------
__global__ void scan_partials_kernel(int* __restrict__ partial, int nb,
                                     int* __restrict__ indptr, int N) {
    int lane = threadIdx.x & 63;
    int orig = (lane < nb) ? partial[lane] : 0;
    int v = orig;
#pragma unroll
    for (int off = 1; off < 64; off <<= 1) {
        int u = __shfl(v, lane - off, 64);
        if (lane >= off) v += u;
    }
    int tot = __shfl(v, nb - 1, 64);
    if (lane < nb) partial[lane] = v - orig;   // exclusive
    if (lane == 0) indptr[N] = tot;
}

// ---------- P3: per-chunk scan + indptr/cursor/dinv ----------
__global__ __launch_bounds__(1024) void scan_chunk_kernel(const int* __restrict__ counts,
        const int* __restrict__ partial, int* __restrict__ indptr, int* __restrict__ cursor,
        float* __restrict__ dinv, int n) {
    __shared__ int sh[1024];
    int b = blockIdx.x;
    int i = b * 1024 + threadIdx.x;
    int v = (i < n) ? counts[i] : 0;
    sh[threadIdx.x] = v;
    __syncthreads();
    for (int off = 1; off < 1024; off <<= 1) {
        int t = (threadIdx.x >= off) ? sh[threadIdx.x - off] : 0;
        __syncthreads();
        sh[threadIdx.x] += t;
        __syncthreads();
    }
    if (i < n) {
        int e = partial[b] + sh[threadIdx.x] - v;
        indptr[i] = e;
        cursor[i] = e;
        dinv[i] = rsqrtf((float)(v + 1));   // self-loop => deg >= 1
    }
}

__global__ void scatter_kernel(const int* __restrict__ src, const int* __restrict__ dst,
                               int* __restrict__ cursor, int* __restrict__ csr_src, int E) {
    int e = blockIdx.x * blockDim.x + threadIdx.x;
    if (e < E) {
        int d = dst[e];
        int pos = atomicAdd(&cursor[d], 1);
        csr_src[pos] = src[e];
    }
}

// ---------- W transpose + bf16 hi/lo split: W[K][256] -> WThi/WTlo [256][K] ----------
__global__ void wsplit_kernel(const void* __restrict__ W, unsigned short* __restrict__ WThi,
                              unsigned short* __restrict__ WTlo, int K,
                              const int* __restrict__ flag) {
    int idx = blockIdx.x * blockDim.x + threadIdx.x;
    if (idx >= K * 256) return;
    int k = idx >> 8;
    int n = idx & 255;
    float v = (*flag != 0) ? ((const float*)W)[idx] : b2f(((const unsigned short*)W)[idx]);
    unsigned short h = f2b(v);
    float r = v - b2f(h);
    WThi[n * K + k] = h;
    WTlo[n * K + k] = f2b(r);
}

// ---------- LDS-staged split-bf16 MFMA GEMM: C[M,256] = A[M,K] @ W[K,256] ----------
// block = 256 thr / 4 waves; tile 64 rows x 256 cols; wave w: all rows x cols [64w,64w+64).
// A[64][32] staged in LDS hi/lo bf16 (stride 40 ushort). C/D: col=lane&15, row=grp*4+reg.
// AF32: 3 MFMA terms (AhWh+AlWh+AhWl). bf16 A: 2 terms.
#define ASTRIDE 40
template<int K, bool AF32>
__device__ __forceinline__ void gemm_loop(const void* __restrict__ A,
        const unsigned short* __restrict__ WThi, const unsigned short* __restrict__ WTlo,
        unsigned short* __restrict__ C, int M,
        unsigned short* Ahi, unsigned short* Alo) {
    const float* A32 = (const float*)A;
    const unsigned short* A16 = (const unsigned short*)A;
    int t = threadIdx.x;
    int lane = t & 63, wv = t >> 6;
    int n0 = lane & 15, grp = lane >> 4;
    int row0 = blockIdx.x * 64;
    int srow = min(row0 + (t >> 2), M - 1);   // staging: 4 threads/row
    int sseg = (t & 3) * 8;                    // 8 elems each

    f32x4 acc[4][4];                           // [row-tile][col-tile]
#pragma unroll
    for (int rt = 0; rt < 4; ++rt)
#pragma unroll
        for (int j = 0; j < 4; ++j) acc[rt][j] = (f32x4){0.f, 0.f, 0.f, 0.f};

    for (int kk = 0; kk < K / 32; ++kk) {
        int kof = kk * 32;
        if (AF32) {
            const float* p = A32 + (size_t)srow * K + kof + sseg;
            float4 v0 = *(const float4*)p;
            float4 v1 = *(const float4*)(p + 4);
            float vv[8] = {v0.x, v0.y, v0.z, v0.w, v1.x, v1.y, v1.z, v1.w};
            bf16x8 hv, lv;
#pragma unroll
            for (int j = 0; j < 8; ++j) {
                unsigned short h = f2b(vv[j]);
                float r = vv[j] - b2f(h);
                hv[j] = (short)h;
                lv[j] = (short)f2b(r);
            }
            *(bf16x8*)(Ahi + (t >> 2) * ASTRIDE + sseg) = hv;
            *(bf16x8*)(Alo + (t >> 2) * ASTRIDE + sseg) = lv;
        } else {
            bf16x8 u = *(const bf16x8*)(A16 + (size_t)srow * K + kof + sseg);
            *(bf16x8*)(Ahi + (t >> 2) * ASTRIDE + sseg) = u;
        }
        __syncthreads();
        int kfrag = kof + grp * 8;
        bf16x8 bh[4], bl[4];
#pragma unroll
        for (int j = 0; j < 4; ++j) {
            int ct = wv * 4 + j;
            size_t bo = (size_t)(ct * 16 + n0) * K + kfrag;
            bh[j] = *(const bf16x8*)(WThi + bo);
            bl[j] = *(const bf16x8*)(WTlo + bo);
        }
#pragma unroll
        for (int rt = 0; rt < 4; ++rt) {
            bf16x8 ah = *(const bf16x8*)(Ahi + (rt * 16 + n0) * ASTRIDE + grp * 8);
            bf16x8 al;
            if (AF32) al = *(const bf16x8*)(Alo + (rt * 16 + n0) * ASTRIDE + grp * 8);
#pragma unroll
            for (int j = 0; j < 4; ++j) {
                acc[rt][j] = __builtin_amdgcn_mfma_f32_16x16x32_bf16(ah, bh[j], acc[rt][j], 0, 0, 0);
                if (AF32)
                    acc[rt][j] = __builtin_amdgcn_mfma_f32_16x16x32_bf16(al, bh[j], acc[rt][j], 0, 0, 0);
                acc[rt][j] = __builtin_amdgcn_mfma_f32_16x16x32_bf16(ah, bl[j], acc[rt][j], 0, 0, 0);
            }
        }
        __syncthreads();
    }
#pragma unroll
    for (int rt = 0; rt < 4; ++rt) {
#pragma unroll
        for (int j = 0; j < 4; ++j) {
#pragma unroll
            for (int reg = 0; reg < 4; ++reg) {
                int row = row0 + rt * 16 + grp * 4 + reg;
                if (row < M)
                    C[(size_t)row * 256 + (wv * 4 + j) * 16 + n0] = f2b(acc[rt][j][reg]);
            }
        }
    }
}

template<int K>
__global__ __launch_bounds__(256) void gemm_tiled(const void* __restrict__ A,
        const unsigned short* __restrict__ WThi, const unsigned short* __restrict__ WTlo,
        unsigned short* __restrict__ C, int M, const int* __restrict__ flag, int a_is_bf16) {
    __shared__ unsigned short Ahi[64 * ASTRIDE];
    __shared__ unsigned short Alo[64 * ASTRIDE];
    bool af32 = (!a_is_bf16) && (*flag != 0);
    if (af32)
        gemm_loop<K, true>(A, WThi, WTlo, C, M, Ahi, Alo);
    else
        gemm_loop<K, false>(A, WThi, WTlo, C, M, Ahi, Alo);
}

// ---------- GCN aggregation (bf16 h in, bf16 out, f32 accum) ----------
__global__ __launch_bounds__(256) void aggregate_kernel(const unsigned short* __restrict__ h,
        const int* __restrict__ indptr, const int* __restrict__ csr_src,
        const float* __restrict__ dinv, const void* __restrict__ bias,
        unsigned short* __restrict__ out, int n, int do_relu, const int* __restrict__ flag) {
    int wave = threadIdx.x >> 6;
    int lane = threadIdx.x & 63;
    int v = blockIdx.x * 4 + wave;
    if (v >= n) return;
    int beg = indptr[v];
    int end = indptr[v + 1];
    float dv = dinv[v];
    ushort4 hv = *(const ushort4*)(h + (size_t)v * 256 + lane * 4);
    float a0 = dv * b2f(hv.x), a1 = dv * b2f(hv.y), a2 = dv * b2f(hv.z), a3 = dv * b2f(hv.w);
    for (int e = beg; e < end; ++e) {
        int s = csr_src[e];
        float w = dinv[s];
        ushort4 hs = *(const ushort4*)(h + (size_t)s * 256 + lane * 4);
        a0 += w * b2f(hs.x); a1 += w * b2f(hs.y); a2 += w * b2f(hs.z); a3 += w * b2f(hs.w);
    }
    float4 bb;
    if (*flag != 0) {
        bb = *(const float4*)((const float*)bias + lane * 4);
    } else {
        ushort4 bu = *(const ushort4*)((const unsigned short*)bias + lane * 4);
        bb.x = b2f(bu.x); bb.y = b2f(bu.y); bb.z = b2f(bu.z); bb.w = b2f(bu.w);
    }
    float o0 = dv * a0 + bb.x;
    float o1 = dv * a1 + bb.y;
    float o2 = dv * a2 + bb.z;
    float o3 = dv * a3 + bb.w;
    if (do_relu) {
        o0 = fmaxf(o0, 0.f); o1 = fmaxf(o1, 0.f); o2 = fmaxf(o2, 0.f); o3 = fmaxf(o3, 0.f);
    }
    ushort4 ov;
    ov.x = f2b(o0); ov.y = f2b(o1); ov.z = f2b(o2); ov.w = f2b(o3);
    *(ushort4*)(out + (size_t)v * 256 + lane * 4) = ov;
}

// ---------- edge scoring via MFMA: 16 edges per wave ----------
// A-frag: lane m=lane&15 holds h[src[base+m]][k], k = kk*32 + grp*8 .. +8 (16B load).
// B-frag: lane n=lane&15 holds h[dst[base+n]][k] (same contiguous form).
// C[m][n] = dot(h_src_m, h_dst_n); diagonal m==n is the edge score.
// C/D layout: col=lane&15, row=grp*4+reg -> lane holds diagonal iff (lane&15)>>2 == grp,
// at reg = m&3. Only those 16 lanes write.
__global__ __launch_bounds__(256) void edge_score_mfma(const unsigned short* __restrict__ h,
        const int* __restrict__ src, const int* __restrict__ dst,
        void* __restrict__ out, int E, const int* __restrict__ flag) {
    int lane = threadIdx.x & 63;
    int wv = threadIdx.x >> 6;
    int base = (blockIdx.x * 4 + wv) * 16;
    if (base >= E) return;
    int m = lane & 15, grp = lane >> 4;
    int e = base + m;
    int ec = min(e, E - 1);
    int s = src[ec], d = dst[ec];
    const unsigned short* hs = h + (size_t)s * 256 + grp * 8;
    const unsigned short* hd = h + (size_t)d * 256 + grp * 8;
    f32x4 acc = {0.f, 0.f, 0.f, 0.f};
#pragma unroll
    for (int kk = 0; kk < 8; ++kk) {
        bf16x8 a = *(const bf16x8*)(hs + kk * 32);
        bf16x8 b = *(const bf16x8*)(hd + kk * 32);
        acc = __builtin_amdgcn_mfma_f32_16x16x32_bf16(a, b, acc, 0, 0, 0);
    }
    int reg = m - grp * 4;
    if (reg >= 0 && reg < 4 && e < E) {
        float p = (reg == 0) ? acc[0] : (reg == 1) ? acc[1] : (reg == 2) ? acc[2] : acc[3];
        float prob = 1.f / (1.f + __expf(-p));
        if (*flag != 0)
            ((float*)out)[e] = prob;
        else
            ((unsigned short*)out)[e] = f2b(prob);
    }
}

extern "C" void kernel_launch(void* const* d_in, const int* in_sizes, int n_in,
                              void* d_out, int out_size, void* d_ws, size_t ws_size,
                              hipStream_t stream) {
    const void* x  = d_in[0];
    const int* edge_index = (const int*)d_in[1];
    const void* W1 = d_in[2];
    const void* b1 = d_in[3];
    const void* W2 = d_in[4];
    const void* b2 = d_in[5];

    const int N = in_sizes[0] / D_IN;   // 50000
    const int E = in_sizes[1] / 2;      // 800000
    const int* src = edge_index;
    const int* dst = edge_index + E;

    char* ws = (char*)d_ws;
    size_t off = 0;
    auto alloc = [&](size_t bytes) {
        char* p = ws + off;
        off = (off + bytes + 255) & ~(size_t)255;
        return p;
    };
    int* flag     = (int*)alloc(256);
    float* dinv   = (float*)alloc((size_t)N * 4);
    int* counts   = (int*)alloc((size_t)N * 4);
    int* indptr   = (int*)alloc((size_t)(N + 1) * 4);
    int* cursor   = (int*)alloc((size_t)N * 4);
    int* partial  = (int*)alloc(64 * 4);
    int* csr_src  = (int*)alloc((size_t)E * 4);
    unsigned short* W1Thi = (unsigned short*)alloc((size_t)D_IN * 256 * 2);
    unsigned short* W1Tlo = (unsigned short*)alloc((size_t)D_IN * 256 * 2);
    unsigned short* W2Thi = (unsigned short*)alloc((size_t)D_HID * 256 * 2);
    unsigned short* W2Tlo = (unsigned short*)alloc((size_t)D_HID * 256 * 2);
    unsigned short* hA = (unsigned short*)alloc((size_t)N * 256 * 2);   // 25.6 MB
    unsigned short* hB = (unsigned short*)alloc((size_t)N * 256 * 2);   // 25.6 MB

    const int nb = (N + 1023) / 1024;   // 49 <= 64

    detect_dtype_kernel<<<1, 256, 0, stream>>>((const unsigned short*)x, 65536, flag);
    hipMemsetAsync(counts, 0, (size_t)N * 4, stream);
    hist_kernel<<<(E + 255) / 256, 256, 0, stream>>>(dst, counts, E);
    partial_sum_kernel<<<nb, 256, 0, stream>>>(counts, partial, N);
    scan_partials_kernel<<<1, 64, 0, stream>>>(partial, nb, indptr, N);
    scan_chunk_kernel<<<nb, 1024, 0, stream>>>(counts, partial, indptr, cursor, dinv, N);
    scatter_kernel<<<(E + 255) / 256, 256, 0, stream>>>(src, dst, cursor, csr_src, E);
    wsplit_kernel<<<(D_IN * 256 + 255) / 256, 256, 0, stream>>>(W1, W1Thi, W1Tlo, D_IN, flag);
    wsplit_kernel<<<(D_HID * 256 + 255) / 256, 256, 0, stream>>>(W2, W2Thi, W2Tlo, D_HID, flag);

    int ggrid = (N + 63) / 64;
    gemm_tiled<D_IN><<<ggrid, 256, 0, stream>>>(x, W1Thi, W1Tlo, hA, N, flag, 0);
    aggregate_kernel<<<(N + 3) / 4, 256, 0, stream>>>(hA, indptr, csr_src, dinv, b1, hB, N, 1, flag);
    gemm_tiled<D_HID><<<ggrid, 256, 0, stream>>>(hB, W2Thi, W2Tlo, hA, N, flag, 1);
    aggregate_kernel<<<(N + 3) / 4, 256, 0, stream>>>(hA, indptr, csr_src, dinv, b2, hB, N, 0, flag);
    edge_score_mfma<<<(E + 63) / 64, 256, 0, stream>>>(hB, src, dst, d_out, E, flag);
}

// Round 9
// 642.385 us; speedup vs baseline: 1.9610x; 1.1532x over previous
//
#include <hip/hip_runtime.h>
#include <stdint.h>

#define D_IN 512
#define D_HID 256

typedef __attribute__((ext_vector_type(8))) short bf16x8;
typedef __attribute__((ext_vector_type(4))) float f32x4;

__device__ __forceinline__ float b2f(unsigned short u) {
    union { float f; uint32_t i; } x; x.i = ((uint32_t)u) << 16; return x.f;
}
__device__ __forceinline__ unsigned short f2b(float f) {
    union { float f; uint32_t i; } x; x.f = f;
    uint32_t i = x.i;
    uint32_t r = (i + 0x7FFFu + ((i >> 16) & 1u)) >> 16;
    return (unsigned short)r;
}

// ---------- dtype detector (parallel): flag|=1 if raw bits are float32 ----------
// f32 bit pattern -> low-half ushorts ~uniform -> bf16-exp==0xFF expected ~256x in 64K scan;
// genuine bf16 N(0,1) data never has exp==0xFF. flag zeroed by hipMemsetAsync beforehand.
__global__ __launch_bounds__(256) void detect_dtype_kernel(const ushort4* __restrict__ raw,
                                                           int n4, int* __restrict__ flag) {
    int i = blockIdx.x * blockDim.x + threadIdx.x;
    int hit = 0;
    if (i < n4) {
        ushort4 u = raw[i];
        hit = ((((u.x >> 7) & 0xFF) == 0xFF) || (((u.y >> 7) & 0xFF) == 0xFF) ||
               (((u.z >> 7) & 0xFF) == 0xFF) || (((u.w >> 7) & 0xFF) == 0xFF)) ? 1 : 0;
    }
    unsigned long long b = __ballot(hit);
    if ((threadIdx.x & 63) == 0 && b != 0ULL) atomicOr(flag, 1);
}

// ---------- degree histogram ----------
__global__ void hist_kernel(const int* __restrict__ dst, int* __restrict__ counts, int E) {
    int e = blockIdx.x * blockDim.x + threadIdx.x;
    if (e < E) atomicAdd(&counts[dst[e]], 1);
}

// ---------- parallel scan: P1 block partial sums (1024 elems/block) ----------
__global__ __launch_bounds__(256) void partial_sum_kernel(const int* __restrict__ counts,
        int* __restrict__ partial, int n) {
    __shared__ int sh[4];
    int b = blockIdx.x;
    int lane = threadIdx.x & 63, wv = threadIdx.x >> 6;
    int s = 0;
    for (int j = threadIdx.x; j < 1024; j += 256) {
        int i = b * 1024 + j;
        s += (i < n) ? counts[i] : 0;
    }
#pragma unroll
    for (int off = 32; off > 0; off >>= 1) s += __shfl_down(s, off, 64);
    if (lane == 0) sh[wv] = s;
    __syncthreads();
    if (threadIdx.x == 0) partial[b] = sh[0] + sh[1] + sh[2] + sh[3];
}

// ---------- P2: 1-wave exclusive scan of <=64 partials; writes indptr[N]=total ----------
__global__ void scan_partials_kernel(int* __restrict__ partial, int nb,
                                     int* __restrict__ indptr, int N) {
    int lane = threadIdx.x & 63;
    int orig = (lane < nb) ? partial[lane] : 0;
    int v = orig;
#pragma unroll
    for (int off = 1; off < 64; off <<= 1) {
        int u = __shfl(v, lane - off, 64);
        if (lane >= off) v += u;
    }
    int tot = __shfl(v, nb - 1, 64);
    if (lane < nb) partial[lane] = v - orig;   // exclusive
    if (lane == 0) indptr[N] = tot;
}

// ---------- P3: per-chunk scan + indptr/cursor/dinv ----------
__global__ __launch_bounds__(1024) void scan_chunk_kernel(const int* __restrict__ counts,
        const int* __restrict__ partial, int* __restrict__ indptr, int* __restrict__ cursor,
        float* __restrict__ dinv, int n) {
    __shared__ int sh[1024];
    int b = blockIdx.x;
    int i = b * 1024 + threadIdx.x;
    int v = (i < n) ? counts[i] : 0;
    sh[threadIdx.x] = v;
    __syncthreads();
    for (int off = 1; off < 1024; off <<= 1) {
        int t = (threadIdx.x >= off) ? sh[threadIdx.x - off] : 0;
        __syncthreads();
        sh[threadIdx.x] += t;
        __syncthreads();
    }
    if (i < n) {
        int e = partial[b] + sh[threadIdx.x] - v;
        indptr[i] = e;
        cursor[i] = e;
        dinv[i] = rsqrtf((float)(v + 1));   // self-loop => deg >= 1
    }
}

__global__ void scatter_kernel(const int* __restrict__ src, const int* __restrict__ dst,
                               int* __restrict__ cursor, int* __restrict__ csr_src, int E) {
    int e = blockIdx.x * blockDim.x + threadIdx.x;
    if (e < E) {
        int d = dst[e];
        int pos = atomicAdd(&cursor[d], 1);
        csr_src[pos] = src[e];
    }
}

// ---------- W transpose + bf16 hi/lo split: W[K][256] -> WThi/WTlo [256][K] ----------
__global__ void wsplit_kernel(const void* __restrict__ W, unsigned short* __restrict__ WThi,
                              unsigned short* __restrict__ WTlo, int K,
                              const int* __restrict__ flag) {
    int idx = blockIdx.x * blockDim.x + threadIdx.x;
    if (idx >= K * 256) return;
    int k = idx >> 8;
    int n = idx & 255;
    float v = (*flag != 0) ? ((const float*)W)[idx] : b2f(((const unsigned short*)W)[idx]);
    unsigned short h = f2b(v);
    float r = v - b2f(h);
    WThi[n * K + k] = h;
    WTlo[n * K + k] = f2b(r);
}

// ---------- LDS-staged split-bf16 MFMA GEMM: C[M,256] = A[M,K] @ W[K,256] ----------
// block = 256 thr / 4 waves; tile 64 rows x 256 cols; wave w: all rows x cols [64w,64w+64).
// A[64][32] staged in LDS hi/lo bf16 (stride 40 ushort). C/D: col=lane&15, row=grp*4+reg.
// AF32: 3 MFMA terms (AhWh+AlWh+AhWl). bf16 A: 2 terms.
#define ASTRIDE 40
template<int K, bool AF32>
__device__ __forceinline__ void gemm_loop(const void* __restrict__ A,
        const unsigned short* __restrict__ WThi, const unsigned short* __restrict__ WTlo,
        unsigned short* __restrict__ C, int M,
        unsigned short* Ahi, unsigned short* Alo) {
    const float* A32 = (const float*)A;
    const unsigned short* A16 = (const unsigned short*)A;
    int t = threadIdx.x;
    int lane = t & 63, wv = t >> 6;
    int n0 = lane & 15, grp = lane >> 4;
    int row0 = blockIdx.x * 64;
    int srow = min(row0 + (t >> 2), M - 1);   // staging: 4 threads/row
    int sseg = (t & 3) * 8;                    // 8 elems each

    f32x4 acc[4][4];                           // [row-tile][col-tile]
#pragma unroll
    for (int rt = 0; rt < 4; ++rt)
#pragma unroll
        for (int j = 0; j < 4; ++j) acc[rt][j] = (f32x4){0.f, 0.f, 0.f, 0.f};

    for (int kk = 0; kk < K / 32; ++kk) {
        int kof = kk * 32;
        if (AF32) {
            const float* p = A32 + (size_t)srow * K + kof + sseg;
            float4 v0 = *(const float4*)p;
            float4 v1 = *(const float4*)(p + 4);
            float vv[8] = {v0.x, v0.y, v0.z, v0.w, v1.x, v1.y, v1.z, v1.w};
            bf16x8 hv, lv;
#pragma unroll
            for (int j = 0; j < 8; ++j) {
                unsigned short h = f2b(vv[j]);
                float r = vv[j] - b2f(h);
                hv[j] = (short)h;
                lv[j] = (short)f2b(r);
            }
            *(bf16x8*)(Ahi + (t >> 2) * ASTRIDE + sseg) = hv;
            *(bf16x8*)(Alo + (t >> 2) * ASTRIDE + sseg) = lv;
        } else {
            bf16x8 u = *(const bf16x8*)(A16 + (size_t)srow * K + kof + sseg);
            *(bf16x8*)(Ahi + (t >> 2) * ASTRIDE + sseg) = u;
        }
        __syncthreads();
        int kfrag = kof + grp * 8;
        bf16x8 bh[4], bl[4];
#pragma unroll
        for (int j = 0; j < 4; ++j) {
            int ct = wv * 4 + j;
            size_t bo = (size_t)(ct * 16 + n0) * K + kfrag;
            bh[j] = *(const bf16x8*)(WThi + bo);
            bl[j] = *(const bf16x8*)(WTlo + bo);
        }
#pragma unroll
        for (int rt = 0; rt < 4; ++rt) {
            bf16x8 ah = *(const bf16x8*)(Ahi + (rt * 16 + n0) * ASTRIDE + grp * 8);
            bf16x8 al;
            if (AF32) al = *(const bf16x8*)(Alo + (rt * 16 + n0) * ASTRIDE + grp * 8);
#pragma unroll
            for (int j = 0; j < 4; ++j) {
                acc[rt][j] = __builtin_amdgcn_mfma_f32_16x16x32_bf16(ah, bh[j], acc[rt][j], 0, 0, 0);
                if (AF32)
                    acc[rt][j] = __builtin_amdgcn_mfma_f32_16x16x32_bf16(al, bh[j], acc[rt][j], 0, 0, 0);
                acc[rt][j] = __builtin_amdgcn_mfma_f32_16x16x32_bf16(ah, bl[j], acc[rt][j], 0, 0, 0);
            }
        }
        __syncthreads();
    }
#pragma unroll
    for (int rt = 0; rt < 4; ++rt) {
#pragma unroll
        for (int j = 0; j < 4; ++j) {
#pragma unroll
            for (int reg = 0; reg < 4; ++reg) {
                int row = row0 + rt * 16 + grp * 4 + reg;
                if (row < M)
                    C[(size_t)row * 256 + (wv * 4 + j) * 16 + n0] = f2b(acc[rt][j][reg]);
            }
        }
    }
}

template<int K>
__global__ __launch_bounds__(256) void gemm_tiled(const void* __restrict__ A,
        const unsigned short* __restrict__ WThi, const unsigned short* __restrict__ WTlo,
        unsigned short* __restrict__ C, int M, const int* __restrict__ flag, int a_is_bf16) {
    __shared__ unsigned short Ahi[64 * ASTRIDE];
    __shared__ unsigned short Alo[64 * ASTRIDE];
    bool af32 = (!a_is_bf16) && (*flag != 0);
    if (af32)
        gemm_loop<K, true>(A, WThi, WTlo, C, M, Ahi, Alo);
    else
        gemm_loop<K, false>(A, WThi, WTlo, C, M, Ahi, Alo);
}

// ---------- GCN aggregation (bf16 h in, bf16 out, f32 accum) ----------
__global__ __launch_bounds__(256) void aggregate_kernel(const unsigned short* __restrict__ h,
        const int* __restrict__ indptr, const int* __restrict__ csr_src,
        const float* __restrict__ dinv, const void* __restrict__ bias,
        unsigned short* __restrict__ out, int n, int do_relu, const int* __restrict__ flag) {
    int wave = threadIdx.x >> 6;
    int lane = threadIdx.x & 63;
    int v = blockIdx.x * 4 + wave;
    if (v >= n) return;
    int beg = indptr[v];
    int end = indptr[v + 1];
    float dv = dinv[v];
    ushort4 hv = *(const ushort4*)(h + (size_t)v * 256 + lane * 4);
    float a0 = dv * b2f(hv.x), a1 = dv * b2f(hv.y), a2 = dv * b2f(hv.z), a3 = dv * b2f(hv.w);
    for (int e = beg; e < end; ++e) {
        int s = csr_src[e];
        float w = dinv[s];
        ushort4 hs = *(const ushort4*)(h + (size_t)s * 256 + lane * 4);
        a0 += w * b2f(hs.x); a1 += w * b2f(hs.y); a2 += w * b2f(hs.z); a3 += w * b2f(hs.w);
    }
    float4 bb;
    if (*flag != 0) {
        bb = *(const float4*)((const float*)bias + lane * 4);
    } else {
        ushort4 bu = *(const ushort4*)((const unsigned short*)bias + lane * 4);
        bb.x = b2f(bu.x); bb.y = b2f(bu.y); bb.z = b2f(bu.z); bb.w = b2f(bu.w);
    }
    float o0 = dv * a0 + bb.x;
    float o1 = dv * a1 + bb.y;
    float o2 = dv * a2 + bb.z;
    float o3 = dv * a3 + bb.w;
    if (do_relu) {
        o0 = fmaxf(o0, 0.f); o1 = fmaxf(o1, 0.f); o2 = fmaxf(o2, 0.f); o3 = fmaxf(o3, 0.f);
    }
    ushort4 ov;
    ov.x = f2b(o0); ov.y = f2b(o1); ov.z = f2b(o2); ov.w = f2b(o3);
    *(ushort4*)(out + (size_t)v * 256 + lane * 4) = ov;
}

// ---------- edge scoring via MFMA: 16 edges per wave ----------
// A-frag: lane m=lane&15 holds h[src[base+m]][k], k = kk*32 + grp*8 .. +8 (16B load).
// B-frag: lane n=lane&15 holds h[dst[base+n]][k].
// C[m][n] = dot(h_src_m, h_dst_n); diagonal m==n is the edge score.
// C/D layout: col=lane&15, row=grp*4+reg -> lane holds diag iff (lane&15)>>2 == grp.
__global__ __launch_bounds__(256) void edge_score_mfma(const unsigned short* __restrict__ h,
        const int* __restrict__ src, const int* __restrict__ dst,
        void* __restrict__ out, int E, const int* __restrict__ flag) {
    int lane = threadIdx.x & 63;
    int wv = threadIdx.x >> 6;
    int base = (blockIdx.x * 4 + wv) * 16;
    if (base >= E) return;
    int m = lane & 15, grp = lane >> 4;
    int e = base + m;
    int ec = min(e, E - 1);
    int s = src[ec], d = dst[ec];
    const unsigned short* hs = h + (size_t)s * 256 + grp * 8;
    const unsigned short* hd = h + (size_t)d * 256 + grp * 8;
    f32x4 acc = {0.f, 0.f, 0.f, 0.f};
#pragma unroll
    for (int kk = 0; kk < 8; ++kk) {
        bf16x8 a = *(const bf16x8*)(hs + kk * 32);
        bf16x8 b = *(const bf16x8*)(hd + kk * 32);
        acc = __builtin_amdgcn_mfma_f32_16x16x32_bf16(a, b, acc, 0, 0, 0);
    }
    int reg = m - grp * 4;
    if (reg >= 0 && reg < 4 && e < E) {
        float p = (reg == 0) ? acc[0] : (reg == 1) ? acc[1] : (reg == 2) ? acc[2] : acc[3];
        float prob = 1.f / (1.f + __expf(-p));
        if (*flag != 0)
            ((float*)out)[e] = prob;
        else
            ((unsigned short*)out)[e] = f2b(prob);
    }
}

extern "C" void kernel_launch(void* const* d_in, const int* in_sizes, int n_in,
                              void* d_out, int out_size, void* d_ws, size_t ws_size,
                              hipStream_t stream) {
    const void* x  = d_in[0];
    const int* edge_index = (const int*)d_in[1];
    const void* W1 = d_in[2];
    const void* b1 = d_in[3];
    const void* W2 = d_in[4];
    const void* b2 = d_in[5];

    const int N = in_sizes[0] / D_IN;   // 50000
    const int E = in_sizes[1] / 2;      // 800000
    const int* src = edge_index;
    const int* dst = edge_index + E;

    char* ws = (char*)d_ws;
    size_t off = 0;
    auto alloc = [&](size_t bytes) {
        char* p = ws + off;
        off = (off + bytes + 255) & ~(size_t)255;
        return p;
    };
    int* flag     = (int*)alloc(256);
    float* dinv   = (float*)alloc((size_t)N * 4);
    int* counts   = (int*)alloc((size_t)N * 4);
    int* indptr   = (int*)alloc((size_t)(N + 1) * 4);
    int* cursor   = (int*)alloc((size_t)N * 4);
    int* partial  = (int*)alloc(64 * 4);
    int* csr_src  = (int*)alloc((size_t)E * 4);
    unsigned short* W1Thi = (unsigned short*)alloc((size_t)D_IN * 256 * 2);
    unsigned short* W1Tlo = (unsigned short*)alloc((size_t)D_IN * 256 * 2);
    unsigned short* W2Thi = (unsigned short*)alloc((size_t)D_HID * 256 * 2);
    unsigned short* W2Tlo = (unsigned short*)alloc((size_t)D_HID * 256 * 2);
    unsigned short* hA = (unsigned short*)alloc((size_t)N * 256 * 2);   // 25.6 MB
    unsigned short* hB = (unsigned short*)alloc((size_t)N * 256 * 2);   // 25.6 MB

    const int nb = (N + 1023) / 1024;   // 49 <= 64

    hipMemsetAsync(flag, 0, 4, stream);
    hipMemsetAsync(counts, 0, (size_t)N * 4, stream);
    detect_dtype_kernel<<<64, 256, 0, stream>>>((const ushort4*)x, 16384, flag);
    hist_kernel<<<(E + 255) / 256, 256, 0, stream>>>(dst, counts, E);
    partial_sum_kernel<<<nb, 256, 0, stream>>>(counts, partial, N);
    scan_partials_kernel<<<1, 64, 0, stream>>>(partial, nb, indptr, N);
    scan_chunk_kernel<<<nb, 1024, 0, stream>>>(counts, partial, indptr, cursor, dinv, N);
    scatter_kernel<<<(E + 255) / 256, 256, 0, stream>>>(src, dst, cursor, csr_src, E);
    wsplit_kernel<<<(D_IN * 256 + 255) / 256, 256, 0, stream>>>(W1, W1Thi, W1Tlo, D_IN, flag);
    wsplit_kernel<<<(D_HID * 256 + 255) / 256, 256, 0, stream>>>(W2, W2Thi, W2Tlo, D_HID, flag);

    int ggrid = (N + 63) / 64;
    gemm_tiled<D_IN><<<ggrid, 256, 0, stream>>>(x, W1Thi, W1Tlo, hA, N, flag, 0);
    aggregate_kernel<<<(N + 3) / 4, 256, 0, stream>>>(hA, indptr, csr_src, dinv, b1, hB, N, 1, flag);
    gemm_tiled<D_HID><<<ggrid, 256, 0, stream>>>(hB, W2Thi, W2Tlo, hA, N, flag, 1);
    aggregate_kernel<<<(N + 3) / 4, 256, 0, stream>>>(hA, indptr, csr_src, dinv, b2, hB, N, 0, flag);
    edge_score_mfma<<<(E + 63) / 64, 256, 0, stream>>>(hB, src, dst, d_out, E, flag);
}

// Round 10
// 613.776 us; speedup vs baseline: 2.0524x; 1.0466x over previous
//
#include <hip/hip_runtime.h>
#include <stdint.h>

#define D_IN 512
#define D_HID 256

typedef __attribute__((ext_vector_type(8))) short bf16x8;
typedef __attribute__((ext_vector_type(4))) float f32x4;

__device__ __forceinline__ float b2f(unsigned short u) {
    union { float f; uint32_t i; } x; x.i = ((uint32_t)u) << 16; return x.f;
}
__device__ __forceinline__ unsigned short f2b(float f) {
    union { float f; uint32_t i; } x; x.f = f;
    uint32_t i = x.i;
    uint32_t r = (i + 0x7FFFu + ((i >> 16) & 1u)) >> 16;
    return (unsigned short)r;
}

// async global->LDS 16B copy; dest is wave-uniform base + lane*16 (HW rule)
__device__ __forceinline__ void async_copy16(const unsigned short* g, unsigned short* lds) {
    __builtin_amdgcn_global_load_lds((const __attribute__((address_space(1))) unsigned int*)g,
                                     (__attribute__((address_space(3))) unsigned int*)lds,
                                     16, 0, 0);
}

// ---------- dtype detector (parallel): flag|=1 if raw bits are float32 ----------
__global__ __launch_bounds__(256) void detect_dtype_kernel(const ushort4* __restrict__ raw,
                                                           int n4, int* __restrict__ flag) {
    int i = blockIdx.x * blockDim.x + threadIdx.x;
    int hit = 0;
    if (i < n4) {
        ushort4 u = raw[i];
        hit = ((((u.x >> 7) & 0xFF) == 0xFF) || (((u.y >> 7) & 0xFF) == 0xFF) ||
               (((u.z >> 7) & 0xFF) == 0xFF) || (((u.w >> 7) & 0xFF) == 0xFF)) ? 1 : 0;
    }
    unsigned long long b = __ballot(hit);
    if ((threadIdx.x & 63) == 0 && b != 0ULL) atomicOr(flag, 1);
}

// ---------- x cast to bf16 (f32 -> RNE round; bf16 -> copy) ----------
__global__ __launch_bounds__(256) void xcast_kernel(const void* __restrict__ X,
        unsigned short* __restrict__ xh, int n4, const int* __restrict__ flag) {
    int i = blockIdx.x * blockDim.x + threadIdx.x;   // group of 4 elems
    if (i >= n4) return;
    ushort4 o;
    if (*flag != 0) {
        float4 v = ((const float4*)X)[i];
        o.x = f2b(v.x); o.y = f2b(v.y); o.z = f2b(v.z); o.w = f2b(v.w);
    } else {
        o = ((const ushort4*)X)[i];
    }
    ((ushort4*)xh)[i] = o;
}

// ---------- degree histogram ----------
__global__ void hist_kernel(const int* __restrict__ dst, int* __restrict__ counts, int E) {
    int e = blockIdx.x * blockDim.x + threadIdx.x;
    if (e < E) atomicAdd(&counts[dst[e]], 1);
}

// ---------- parallel scan P1/P2/P3 ----------
__global__ __launch_bounds__(256) void partial_sum_kernel(const int* __restrict__ counts,
        int* __restrict__ partial, int n) {
    __shared__ int sh[4];
    int b = blockIdx.x;
    int lane = threadIdx.x & 63, wv = threadIdx.x >> 6;
    int s = 0;
    for (int j = threadIdx.x; j < 1024; j += 256) {
        int i = b * 1024 + j;
        s += (i < n) ? counts[i] : 0;
    }
#pragma unroll
    for (int off = 32; off > 0; off >>= 1) s += __shfl_down(s, off, 64);
    if (lane == 0) sh[wv] = s;
    __syncthreads();
    if (threadIdx.x == 0) partial[b] = sh[0] + sh[1] + sh[2] + sh[3];
}

__global__ void scan_partials_kernel(int* __restrict__ partial, int nb,
                                     int* __restrict__ indptr, int N) {
    int lane = threadIdx.x & 63;
    int orig = (lane < nb) ? partial[lane] : 0;
    int v = orig;
#pragma unroll
    for (int off = 1; off < 64; off <<= 1) {
        int u = __shfl(v, lane - off, 64);
        if (lane >= off) v += u;
    }
    int tot = __shfl(v, nb - 1, 64);
    if (lane < nb) partial[lane] = v - orig;
    if (lane == 0) indptr[N] = tot;
}

__global__ __launch_bounds__(1024) void scan_chunk_kernel(const int* __restrict__ counts,
        const int* __restrict__ partial, int* __restrict__ indptr, int* __restrict__ cursor,
        float* __restrict__ dinv, int n) {
    __shared__ int sh[1024];
    int b = blockIdx.x;
    int i = b * 1024 + threadIdx.x;
    int v = (i < n) ? counts[i] : 0;
    sh[threadIdx.x] = v;
    __syncthreads();
    for (int off = 1; off < 1024; off <<= 1) {
        int t = (threadIdx.x >= off) ? sh[threadIdx.x - off] : 0;
        __syncthreads();
        sh[threadIdx.x] += t;
        __syncthreads();
    }
    if (i < n) {
        int e = partial[b] + sh[threadIdx.x] - v;
        indptr[i] = e;
        cursor[i] = e;
        dinv[i] = rsqrtf((float)(v + 1));
    }
}

__global__ void scatter_kernel(const int* __restrict__ src, const int* __restrict__ dst,
                               int* __restrict__ cursor, int* __restrict__ csr_src, int E) {
    int e = blockIdx.x * blockDim.x + threadIdx.x;
    if (e < E) {
        int d = dst[e];
        int pos = atomicAdd(&cursor[d], 1);
        csr_src[pos] = src[e];
    }
}

// ---------- W transpose to bf16: W[K][256] -> WT[256][K] ----------
__global__ void wT_kernel(const void* __restrict__ W, unsigned short* __restrict__ WT,
                          int K, const int* __restrict__ flag) {
    int idx = blockIdx.x * blockDim.x + threadIdx.x;
    if (idx >= K * 256) return;
    int k = idx >> 8;
    int n = idx & 255;
    float v = (*flag != 0) ? ((const float*)W)[idx] : b2f(((const unsigned short*)W)[idx]);
    WT[n * K + k] = f2b(v);
}

// ---------- pure-bf16 MFMA GEMM: C[M,256] = A[M,K] @ W[K,256] (A,WT bf16) ----------
// block = 256 thr / 4 waves; tile 64 rows x 256 cols; wave w: cols [64w, 64w+64).
// BK=64: A[64][64] staged via global_load_lds (16B/lane). LDS layout row-major 128B rows
// with 16B-segment rotation seg' = (seg + row) & 7 -> conflict-free ds_read_b128.
// Frag layout (validated r4-r9): A lane m=lane&15 row, k=grp*8; B = WT row (ct*16+n0);
// C/D: col = lane&15, row = grp*4 + reg.
template<int K>
__global__ __launch_bounds__(256) void gemm_bf16(const unsigned short* __restrict__ A,
        const unsigned short* __restrict__ WT, unsigned short* __restrict__ C, int M) {
    __shared__ unsigned short As[64 * 64];    // 8 KB
    int t = threadIdx.x;
    int lane = t & 63, wv = t >> 6;
    int n0 = lane & 15, grp = lane >> 4;
    int row0 = blockIdx.x * 64;

    // staging coords: wave wv, issue j covers rows [wv*16 + j*8, +8), lane l -> row +l/8, seg' l%8
    int srow = wv * 16 + (lane >> 3);         // + j*8 added per issue
    int segp = lane & 7;

    f32x4 acc[4][4];
#pragma unroll
    for (int rt = 0; rt < 4; ++rt)
#pragma unroll
        for (int ct = 0; ct < 4; ++ct) acc[rt][ct] = (f32x4){0.f, 0.f, 0.f, 0.f};

    for (int kk = 0; kk < K / 64; ++kk) {
        int kof = kk * 64;
#pragma unroll
        for (int j = 0; j < 2; ++j) {
            int row = srow + j * 8;
            int s = (segp - row) & 7;                       // global 16B-seg for this dest slot
            const unsigned short* g = A + (size_t)min(row0 + row, M - 1) * K + kof + s * 8;
            async_copy16(g, As + wv * 1024 + j * 512);      // ushort units: 1024 = 2KB/wave
        }
        __syncthreads();
        // W fragments: 8 x 16B from L2-hot WT
        bf16x8 bw[4][2];
#pragma unroll
        for (int ct = 0; ct < 4; ++ct)
#pragma unroll
            for (int h = 0; h < 2; ++h)
                bw[ct][h] = *(const bf16x8*)(WT + (size_t)((wv * 4 + ct) * 16 + n0) * K
                                             + kof + h * 32 + grp * 8);
        // A fragments from LDS + MFMA
#pragma unroll
        for (int rt = 0; rt < 4; ++rt) {
            int r = rt * 16 + n0;
#pragma unroll
            for (int h = 0; h < 2; ++h) {
                int sp = (h * 4 + grp + r) & 7;
                bf16x8 a = *(const bf16x8*)(As + r * 64 + sp * 8);
#pragma unroll
                for (int ct = 0; ct < 4; ++ct)
                    acc[rt][ct] = __builtin_amdgcn_mfma_f32_16x16x32_bf16(a, bw[ct][h],
                                                                          acc[rt][ct], 0, 0, 0);
            }
        }
        __syncthreads();
    }
#pragma unroll
    for (int rt = 0; rt < 4; ++rt) {
#pragma unroll
        for (int ct = 0; ct < 4; ++ct) {
#pragma unroll
            for (int reg = 0; reg < 4; ++reg) {
                int row = row0 + rt * 16 + grp * 4 + reg;
                if (row < M)
                    C[(size_t)row * 256 + (wv * 4 + ct) * 16 + n0] = f2b(acc[rt][ct][reg]);
            }
        }
    }
}

// ---------- GCN aggregation (bf16 h in, bf16 out, f32 accum) ----------
__global__ __launch_bounds__(256) void aggregate_kernel(const unsigned short* __restrict__ h,
        const int* __restrict__ indptr, const int* __restrict__ csr_src,
        const float* __restrict__ dinv, const void* __restrict__ bias,
        unsigned short* __restrict__ out, int n, int do_relu, const int* __restrict__ flag) {
    int wave = threadIdx.x >> 6;
    int lane = threadIdx.x & 63;
    int v = blockIdx.x * 4 + wave;
    if (v >= n) return;
    int beg = indptr[v];
    int end = indptr[v + 1];
    float dv = dinv[v];
    ushort4 hv = *(const ushort4*)(h + (size_t)v * 256 + lane * 4);
    float a0 = dv * b2f(hv.x), a1 = dv * b2f(hv.y), a2 = dv * b2f(hv.z), a3 = dv * b2f(hv.w);
    for (int e = beg; e < end; ++e) {
        int s = csr_src[e];
        float w = dinv[s];
        ushort4 hs = *(const ushort4*)(h + (size_t)s * 256 + lane * 4);
        a0 += w * b2f(hs.x); a1 += w * b2f(hs.y); a2 += w * b2f(hs.z); a3 += w * b2f(hs.w);
    }
    float4 bb;
    if (*flag != 0) {
        bb = *(const float4*)((const float*)bias + lane * 4);
    } else {
        ushort4 bu = *(const ushort4*)((const unsigned short*)bias + lane * 4);
        bb.x = b2f(bu.x); bb.y = b2f(bu.y); bb.z = b2f(bu.z); bb.w = b2f(bu.w);
    }
    float o0 = dv * a0 + bb.x;
    float o1 = dv * a1 + bb.y;
    float o2 = dv * a2 + bb.z;
    float o3 = dv * a3 + bb.w;
    if (do_relu) {
        o0 = fmaxf(o0, 0.f); o1 = fmaxf(o1, 0.f); o2 = fmaxf(o2, 0.f); o3 = fmaxf(o3, 0.f);
    }
    ushort4 ov;
    ov.x = f2b(o0); ov.y = f2b(o1); ov.z = f2b(o2); ov.w = f2b(o3);
    *(ushort4*)(out + (size_t)v * 256 + lane * 4) = ov;
}

// ---------- edge scoring via MFMA: 16 edges per wave ----------
__global__ __launch_bounds__(256) void edge_score_mfma(const unsigned short* __restrict__ h,
        const int* __restrict__ src, const int* __restrict__ dst,
        void* __restrict__ out, int E, const int* __restrict__ flag) {
    int lane = threadIdx.x & 63;
    int wv = threadIdx.x >> 6;
    int base = (blockIdx.x * 4 + wv) * 16;
    if (base >= E) return;
    int m = lane & 15, grp = lane >> 4;
    int e = base + m;
    int ec = min(e, E - 1);
    int s = src[ec], d = dst[ec];
    const unsigned short* hs = h + (size_t)s * 256 + grp * 8;
    const unsigned short* hd = h + (size_t)d * 256 + grp * 8;
    f32x4 acc = {0.f, 0.f, 0.f, 0.f};
#pragma unroll
    for (int kk = 0; kk < 8; ++kk) {
        bf16x8 a = *(const bf16x8*)(hs + kk * 32);
        bf16x8 b = *(const bf16x8*)(hd + kk * 32);
        acc = __builtin_amdgcn_mfma_f32_16x16x32_bf16(a, b, acc, 0, 0, 0);
    }
    int reg = m - grp * 4;
    if (reg >= 0 && reg < 4 && e < E) {
        float p = (reg == 0) ? acc[0] : (reg == 1) ? acc[1] : (reg == 2) ? acc[2] : acc[3];
        float prob = 1.f / (1.f + __expf(-p));
        if (*flag != 0)
            ((float*)out)[e] = prob;
        else
            ((unsigned short*)out)[e] = f2b(prob);
    }
}

extern "C" void kernel_launch(void* const* d_in, const int* in_sizes, int n_in,
                              void* d_out, int out_size, void* d_ws, size_t ws_size,
                              hipStream_t stream) {
    const void* x  = d_in[0];
    const int* edge_index = (const int*)d_in[1];
    const void* W1 = d_in[2];
    const void* b1 = d_in[3];
    const void* W2 = d_in[4];
    const void* b2 = d_in[5];

    const int N = in_sizes[0] / D_IN;   // 50000
    const int E = in_sizes[1] / 2;      // 800000
    const int* src = edge_index;
    const int* dst = edge_index + E;

    char* ws = (char*)d_ws;
    size_t off = 0;
    auto alloc = [&](size_t bytes) {
        char* p = ws + off;
        off = (off + bytes + 255) & ~(size_t)255;
        return p;
    };
    int* flag     = (int*)alloc(256);
    float* dinv   = (float*)alloc((size_t)N * 4);
    int* counts   = (int*)alloc((size_t)N * 4);
    int* indptr   = (int*)alloc((size_t)(N + 1) * 4);
    int* cursor   = (int*)alloc((size_t)N * 4);
    int* partial  = (int*)alloc(64 * 4);
    int* csr_src  = (int*)alloc((size_t)E * 4);
    unsigned short* W1T = (unsigned short*)alloc((size_t)D_IN * 256 * 2);
    unsigned short* W2T = (unsigned short*)alloc((size_t)D_HID * 256 * 2);
    unsigned short* xh  = (unsigned short*)alloc((size_t)N * D_IN * 2);   // 51.2 MB
    unsigned short* hA  = (unsigned short*)alloc((size_t)N * 256 * 2);    // 25.6 MB
    unsigned short* hB  = (unsigned short*)alloc((size_t)N * 256 * 2);    // 25.6 MB

    const int nb = (N + 1023) / 1024;   // 49 <= 64

    hipMemsetAsync(flag, 0, 4, stream);
    hipMemsetAsync(counts, 0, (size_t)N * 4, stream);
    detect_dtype_kernel<<<64, 256, 0, stream>>>((const ushort4*)x, 16384, flag);
    xcast_kernel<<<(N * D_IN / 4 + 255) / 256, 256, 0, stream>>>(x, xh, N * D_IN / 4, flag);
    hist_kernel<<<(E + 255) / 256, 256, 0, stream>>>(dst, counts, E);
    partial_sum_kernel<<<nb, 256, 0, stream>>>(counts, partial, N);
    scan_partials_kernel<<<1, 64, 0, stream>>>(partial, nb, indptr, N);
    scan_chunk_kernel<<<nb, 1024, 0, stream>>>(counts, partial, indptr, cursor, dinv, N);
    scatter_kernel<<<(E + 255) / 256, 256, 0, stream>>>(src, dst, cursor, csr_src, E);
    wT_kernel<<<(D_IN * 256 + 255) / 256, 256, 0, stream>>>(W1, W1T, D_IN, flag);
    wT_kernel<<<(D_HID * 256 + 255) / 256, 256, 0, stream>>>(W2, W2T, D_HID, flag);

    int ggrid = (N + 63) / 64;
    gemm_bf16<D_IN><<<ggrid, 256, 0, stream>>>(xh, W1T, hA, N);
    aggregate_kernel<<<(N + 3) / 4, 256, 0, stream>>>(hA, indptr, csr_src, dinv, b1, hB, N, 1, flag);
    gemm_bf16<D_HID><<<ggrid, 256, 0, stream>>>(hB, W2T, hA, N);
    aggregate_kernel<<<(N + 3) / 4, 256, 0, stream>>>(hA, indptr, csr_src, dinv, b2, hB, N, 0, flag);
    edge_score_mfma<<<(E + 63) / 64, 256, 0, stream>>>(hB, src, dst, d_out, E, flag);
}